// Round 1
// baseline (739.918 us; speedup 1.0000x reference)
//
#include <hip/hip_runtime.h>
#include <math.h>

#define BB 16
#define FF 60
#define NPTS 512
#define EMB 128
#define SS 61
#define EPSV 1e-5f

__device__ __forceinline__ unsigned mapKey(float f){
  unsigned u = __float_as_uint(f);
  return (u & 0x80000000u) ? ~u : (u | 0x80000000u);
}
__device__ __forceinline__ float unmapKey(unsigned k){
  unsigned u = (k & 0x80000000u) ? (k & 0x7fffffffu) : ~k;
  return __uint_as_float(u);
}
__device__ __forceinline__ unsigned f2bf(float f){
  unsigned u = __float_as_uint(f);
  return (u + 0x7fffu + ((u >> 16) & 1u)) >> 16;
}

// ---------------- encoder: per-point MLP 3->64->128->128 + frame max-pool ----------------
__global__ __launch_bounds__(256) void enc_kernel(
    const float* __restrict__ x,
    const float* __restrict__ ew1, const float* __restrict__ eb1,
    const float* __restrict__ ew2, const float* __restrict__ eb2,
    const float* __restrict__ ew3, const float* __restrict__ eb3,
    unsigned* __restrict__ ymaxKey)
{
  __shared__ unsigned h2s[256 * 64];   // 64KB: per-thread 64 words of packed bf16 pairs
  const int tid = threadIdx.x;
  const int frame = blockIdx.x >> 1;               // 0..959
  const int p = ((blockIdx.x & 1) << 8) + tid;     // 0..511
  const float* xp = x + ((size_t)frame * NPTS + p) * 3;
  const float x0 = xp[0], x1 = xp[1], x2 = xp[2];

  // layer 1: 3 -> 64, relu (weights uniform -> scalar loads)
  float h1[64];
#pragma unroll
  for (int j = 0; j < 64; j++) {
    float a = fmaf(x0, ew1[j], fmaf(x1, ew1[64 + j], fmaf(x2, ew1[128 + j], eb1[j])));
    h1[j] = fmaxf(a, 0.f);
  }

  unsigned* hrow = h2s + tid * 64;
  const unsigned sw = (unsigned)(tid & 31);

  // layer 2: 64 -> 128, relu, store bf16 pairs in LDS (swizzled, conflict-free)
  for (int nc = 0; nc < 4; nc++) {
    float acc[32];
#pragma unroll
    for (int n = 0; n < 32; n++) acc[n] = eb2[nc * 32 + n];
#pragma unroll
    for (int k = 0; k < 64; k++) {
      const float hk = h1[k];
      const float* wr = ew2 + k * 128 + nc * 32;
#pragma unroll
      for (int n = 0; n < 32; n++) acc[n] = fmaf(hk, wr[n], acc[n]);
    }
#pragma unroll
    for (int n = 0; n < 32; n += 2) {
      unsigned u0 = f2bf(fmaxf(acc[n], 0.f));
      unsigned u1 = f2bf(fmaxf(acc[n + 1], 0.f));
      unsigned q = (unsigned)(nc * 16 + (n >> 1));
      hrow[q ^ sw] = u0 | (u1 << 16);
    }
  }

  // layer 3: 128 -> 128 (no relu), wave-max, one atomic per wave
  for (int nc = 0; nc < 4; nc++) {
    float acc[32];
#pragma unroll
    for (int n = 0; n < 32; n++) acc[n] = eb3[nc * 32 + n];
#pragma unroll 4
    for (int kk = 0; kk < 64; kk++) {
      unsigned pr = hrow[(unsigned)kk ^ sw];
      float a0 = __uint_as_float(pr << 16);
      float a1 = __uint_as_float(pr & 0xffff0000u);
      const float* w0 = ew3 + (2 * kk) * 128 + nc * 32;
      const float* w1 = w0 + 128;
#pragma unroll
      for (int n = 0; n < 32; n++) {
        acc[n] = fmaf(a0, w0[n], acc[n]);
        acc[n] = fmaf(a1, w1[n], acc[n]);
      }
    }
#pragma unroll
    for (int n = 0; n < 32; n++) {
      float v = acc[n];
      for (int off = 32; off > 0; off >>= 1) v = fmaxf(v, __shfl_xor(v, off, 64));
      if ((tid & 63) == 0) atomicMax(&ymaxKey[frame * 128 + nc * 32 + n], mapKey(v));
    }
  }
}

// ---------------- token assembly: cls + masked frame embeddings + pos enc ----------------
__global__ __launch_bounds__(128) void assemble_kernel(
    const unsigned* __restrict__ ymaxKey, const int* __restrict__ fl,
    const float* __restrict__ cls_token, const float* __restrict__ cls_pos,
    float* __restrict__ y)
{
  const int s = blockIdx.x;        // 0..975
  const int b = s / SS, t = s % SS;
  const int d = threadIdx.x;
  float v;
  if (t == 0) {
    v = cls_token[d] + cls_pos[d];
  } else {
    const int f = t - 1;
    float ym = 0.f;
    if (f < fl[b]) ym = unmapKey(ymaxKey[(b * FF + f) * 128 + d]);
    float ang = (float)f * expf((float)(2 * (d >> 1)) * (-9.210340371976184f / 128.f));
    float pe = (d & 1) ? cosf(ang) : sinf(ang);
    v = ym + pe;
  }
  y[s * 128 + d] = v;
}

// ---------------- qkv projection ----------------
__global__ __launch_bounds__(128) void qkv_kernel(
    const float* __restrict__ y, const float* __restrict__ iw, const float* __restrict__ ib,
    float* __restrict__ qkv)
{
  __shared__ float ys[128];
  const int t = blockIdx.x, d = threadIdx.x;
  ys[d] = y[t * 128 + d];
  __syncthreads();
  for (int part = 0; part < 3; part++) {
    const int j = part * 128 + d;
    const float* wr = iw + j * 128;
    float acc = ib[j];
#pragma unroll 8
    for (int e = 0; e < 128; e++) acc = fmaf(ys[e], wr[e], acc);
    qkv[t * 384 + j] = acc;
  }
}

// ---------------- attention (one wave per (b,h)) ----------------
__global__ __launch_bounds__(64) void attn_kernel(
    const float* __restrict__ qkv, const int* __restrict__ fl,
    float* __restrict__ obuf)
{
  __shared__ float kx[SS][33];
  __shared__ float vx[SS][33];
  __shared__ float sc[64][64];
  const int b = blockIdx.x >> 2, h = blockIdx.x & 3;
  const int tid = threadIdx.x;
  for (int idx = tid; idx < SS * 32; idx += 64) {
    const int t = idx >> 5, d = idx & 31;
    const float* base = qkv + (size_t)(b * SS + t) * 384 + h * 32 + d;
    kx[t][d] = base[128];
    vx[t][d] = base[256];
  }
  __syncthreads();
  const int i = tid;
  if (i < SS) {
    float q[32];
    const float* qp = qkv + (size_t)(b * SS + i) * 384 + h * 32;
#pragma unroll
    for (int d = 0; d < 32; d++) q[d] = qp[d];
    const int f = fl[b];
    float m = -1e30f;
    for (int t = 0; t < SS; t++) {
      float s = 0.f;
#pragma unroll
      for (int d = 0; d < 32; d++) s = fmaf(q[d], kx[t][d], s);
      s *= 0.17677669529663687f;         // 1/sqrt(32)
      if (t > f) s += -1e9f;
      sc[i][t] = s;
      m = fmaxf(m, s);
    }
    float sum = 0.f;
    for (int t = 0; t < SS; t++) {
      float p = expf(sc[i][t] - m);
      sc[i][t] = p;
      sum += p;
    }
    const float inv = 1.f / sum;
    float o[32];
#pragma unroll
    for (int d = 0; d < 32; d++) o[d] = 0.f;
    for (int t = 0; t < SS; t++) {
      const float p = sc[i][t];
#pragma unroll
      for (int d = 0; d < 32; d++) o[d] = fmaf(p, vx[t][d], o[d]);
    }
    float* op = obuf + (size_t)(b * SS + i) * 128 + h * 32;
#pragma unroll
    for (int d = 0; d < 32; d++) op[d] = o[d] * inv;
  }
}

// ---------------- attention out-proj + residual + LN1 (in-place y) ----------------
__global__ __launch_bounds__(128) void proj_ln_kernel(
    const float* __restrict__ obuf, const float* __restrict__ ow, const float* __restrict__ ob,
    const float* __restrict__ g, const float* __restrict__ bb,
    float* __restrict__ y)
{
  __shared__ float os[128];
  __shared__ float rs[128];
  const int t = blockIdx.x, d = threadIdx.x;
  os[d] = obuf[t * 128 + d];
  __syncthreads();
  const float* wr = ow + d * 128;
  float acc = ob[d];
#pragma unroll 8
  for (int e = 0; e < 128; e++) acc = fmaf(os[e], wr[e], acc);
  const float r = y[t * 128 + d] + acc;
  rs[d] = r;
  __syncthreads();
  float s1 = 0.f, s2 = 0.f;
#pragma unroll 8
  for (int e = 0; e < 128; e++) { const float v = rs[e]; s1 += v; s2 = fmaf(v, v, s2); }
  const float mean = s1 * (1.f / 128.f);
  const float var = s2 * (1.f / 128.f) - mean * mean;
  const float inv = 1.f / sqrtf(var + EPSV);
  y[t * 128 + d] = (r - mean) * inv * g[d] + bb[d];
}

// ---------------- FF (128->256 relu ->128) + residual + LN2 (in-place y) ----------------
__global__ __launch_bounds__(128) void ff_ln_kernel(
    const float* __restrict__ w1, const float* __restrict__ b1,
    const float* __restrict__ w2, const float* __restrict__ b2,
    const float* __restrict__ g, const float* __restrict__ bb,
    float* __restrict__ y)
{
  __shared__ float ys[128];
  __shared__ float ffs[256];
  __shared__ float rs[128];
  const int t = blockIdx.x, d = threadIdx.x;
  ys[d] = y[t * 128 + d];
  __syncthreads();
  for (int rr = 0; rr < 2; rr++) {
    const int j = rr * 128 + d;
    const float* wr = w1 + j * 128;
    float acc = b1[j];
#pragma unroll 8
    for (int e = 0; e < 128; e++) acc = fmaf(ys[e], wr[e], acc);
    ffs[j] = fmaxf(acc, 0.f);
  }
  __syncthreads();
  const float* wr2 = w2 + d * 256;
  float acc = b2[d];
#pragma unroll 8
  for (int e = 0; e < 256; e++) acc = fmaf(ffs[e], wr2[e], acc);
  const float r = ys[d] + acc;
  rs[d] = r;
  __syncthreads();
  float s1 = 0.f, s2 = 0.f;
#pragma unroll 8
  for (int e = 0; e < 128; e++) { const float v = rs[e]; s1 += v; s2 = fmaf(v, v, s2); }
  const float mean = s1 * (1.f / 128.f);
  const float var = s2 * (1.f / 128.f) - mean * mean;
  const float inv = 1.f / sqrtf(var + EPSV);
  y[t * 128 + d] = (r - mean) * inv * g[d] + bb[d];
}

// ---------------- classifier head with live batch-norm (single block) ----------------
__global__ __launch_bounds__(256) void head_kernel(
    const float* __restrict__ y, const int* __restrict__ fl,
    const float* __restrict__ fc1w, const float* __restrict__ fc1b,
    const float* __restrict__ bn1g, const float* __restrict__ bn1b,
    const float* __restrict__ fc15w, const float* __restrict__ fc15b,
    const float* __restrict__ bn15g, const float* __restrict__ bn15b,
    const float* __restrict__ fc2w, const float* __restrict__ fc2b,
    const float* __restrict__ bn2g, const float* __restrict__ bn2b,
    const float* __restrict__ fcw, const float* __restrict__ fcb,
    float* __restrict__ out)
{
  __shared__ float zc[16 * 256];
  __shared__ float t1[16 * 128];
  __shared__ float t15[16 * 64];
  __shared__ float t2[16 * 32];
  const int tid = threadIdx.x;

  for (int idx = tid; idx < 16 * 256; idx += 256) {
    const int b = idx >> 8, d = idx & 255;
    zc[idx] = (d < 128) ? y[(size_t)(b * SS) * 128 + d]
                        : y[(size_t)(b * SS + fl[b]) * 128 + (d - 128)];
  }
  __syncthreads();

  // fc1: (16,256)@(256,128)
  for (int idx = tid; idx < 16 * 128; idx += 256) {
    const int b = idx >> 7, j = idx & 127;
    float a = fc1b[j];
    for (int k = 0; k < 256; k++) a = fmaf(zc[b * 256 + k], fc1w[k * 128 + j], a);
    t1[idx] = a;
  }
  __syncthreads();
  if (tid < 128) {
    const int j = tid;
    float s1 = 0.f, s2 = 0.f;
    for (int b = 0; b < 16; b++) { const float v = t1[b * 128 + j]; s1 += v; s2 = fmaf(v, v, s2); }
    const float m = s1 * (1.f / 16.f);
    const float var = s2 * (1.f / 16.f) - m * m;
    const float scl = bn1g[j] / sqrtf(var + EPSV);
    const float sh = bn1b[j] - m * scl;
    for (int b = 0; b < 16; b++) {
      const float v = t1[b * 128 + j] * scl + sh;
      t1[b * 128 + j] = (v > 0.f) ? v : 0.2f * v;
    }
  }
  __syncthreads();

  // fc15: (16,128)@(128,64)
  for (int idx = tid; idx < 16 * 64; idx += 256) {
    const int b = idx >> 6, j = idx & 63;
    float a = fc15b[j];
    for (int k = 0; k < 128; k++) a = fmaf(t1[b * 128 + k], fc15w[k * 64 + j], a);
    t15[idx] = a;
  }
  __syncthreads();
  if (tid < 64) {
    const int j = tid;
    float s1 = 0.f, s2 = 0.f;
    for (int b = 0; b < 16; b++) { const float v = t15[b * 64 + j]; s1 += v; s2 = fmaf(v, v, s2); }
    const float m = s1 * (1.f / 16.f);
    const float var = s2 * (1.f / 16.f) - m * m;
    const float scl = bn15g[j] / sqrtf(var + EPSV);
    const float sh = bn15b[j] - m * scl;
    for (int b = 0; b < 16; b++) {
      const float v = t15[b * 64 + j] * scl + sh;
      t15[b * 64 + j] = (v > 0.f) ? v : 0.2f * v;
    }
  }
  __syncthreads();

  // fc2: (16,64)@(64,32)
  for (int idx = tid; idx < 16 * 32; idx += 256) {
    const int b = idx >> 5, j = idx & 31;
    float a = fc2b[j];
    for (int k = 0; k < 64; k++) a = fmaf(t15[b * 64 + k], fc2w[k * 32 + j], a);
    t2[idx] = a;
  }
  __syncthreads();
  if (tid < 32) {
    const int j = tid;
    float s1 = 0.f, s2 = 0.f;
    for (int b = 0; b < 16; b++) { const float v = t2[b * 32 + j]; s1 += v; s2 = fmaf(v, v, s2); }
    const float m = s1 * (1.f / 16.f);
    const float var = s2 * (1.f / 16.f) - m * m;
    const float scl = bn2g[j] / sqrtf(var + EPSV);
    const float sh = bn2b[j] - m * scl;
    for (int b = 0; b < 16; b++) {
      const float v = t2[b * 32 + j] * scl + sh;
      t2[b * 32 + j] = (v > 0.f) ? v : 0.2f * v;
    }
  }
  __syncthreads();

  // final fc: (16,32)@(32,27)
  for (int idx = tid; idx < 16 * 27; idx += 256) {
    const int b = idx / 27, c = idx % 27;
    float a = fcb[c];
    for (int k = 0; k < 32; k++) a = fmaf(t2[b * 32 + k], fcw[k * 27 + c], a);
    out[b * 27 + c] = a;
  }
}

extern "C" void kernel_launch(void* const* d_in, const int* in_sizes, int n_in,
                              void* d_out, int out_size, void* d_ws, size_t ws_size,
                              hipStream_t stream)
{
  const float* x    = (const float*)d_in[0];
  const int*   fl   = (const int*)d_in[1];
  const float* ew1  = (const float*)d_in[2];  const float* eb1 = (const float*)d_in[3];
  const float* ew2  = (const float*)d_in[4];  const float* eb2 = (const float*)d_in[5];
  const float* ew3  = (const float*)d_in[6];  const float* eb3 = (const float*)d_in[7];
  const float* ctok = (const float*)d_in[8];  const float* cpos = (const float*)d_in[9];
  const float* in_w = (const float*)d_in[10]; const float* in_b = (const float*)d_in[11];
  const float* ow   = (const float*)d_in[12]; const float* ob   = (const float*)d_in[13];
  const float* l1g  = (const float*)d_in[14]; const float* l1b  = (const float*)d_in[15];
  const float* f1w  = (const float*)d_in[16]; const float* f1b  = (const float*)d_in[17];
  const float* f2w  = (const float*)d_in[18]; const float* f2b  = (const float*)d_in[19];
  const float* l2g  = (const float*)d_in[20]; const float* l2b  = (const float*)d_in[21];
  const float* fc1w = (const float*)d_in[22]; const float* fc1b = (const float*)d_in[23];
  const float* bn1g = (const float*)d_in[24]; const float* bn1b = (const float*)d_in[25];
  const float* fc15w= (const float*)d_in[26]; const float* fc15b= (const float*)d_in[27];
  const float* bn15g= (const float*)d_in[28]; const float* bn15b= (const float*)d_in[29];
  const float* fc2w = (const float*)d_in[30]; const float* fc2b = (const float*)d_in[31];
  const float* bn2g = (const float*)d_in[32]; const float* bn2b = (const float*)d_in[33];
  const float* fcw  = (const float*)d_in[34]; const float* fcb  = (const float*)d_in[35];
  float* out = (float*)d_out;

  char* w = (char*)d_ws;
  unsigned* ymaxKey = (unsigned*)w;                                  // 960*128*4 = 491520
  float* ybuf = (float*)(w + 491520);                                // 976*128*4 = 499712
  float* qkvb = (float*)(w + 491520 + 499712);                       // 976*384*4 = 1499136
  float* obuf = (float*)(w + 491520 + 499712 + 1499136);             // 499712

  hipMemsetAsync(ymaxKey, 0, 960 * 128 * 4, stream);
  enc_kernel<<<1920, 256, 0, stream>>>(x, ew1, eb1, ew2, eb2, ew3, eb3, ymaxKey);
  assemble_kernel<<<976, 128, 0, stream>>>(ymaxKey, fl, ctok, cpos, ybuf);
  for (int l = 0; l < 2; l++) {
    qkv_kernel<<<976, 128, 0, stream>>>(ybuf, in_w + l * 384 * 128, in_b + l * 384, qkvb);
    attn_kernel<<<64, 64, 0, stream>>>(qkvb, fl, obuf);
    proj_ln_kernel<<<976, 128, 0, stream>>>(obuf, ow + l * 128 * 128, ob + l * 128,
                                            l1g + l * 128, l1b + l * 128, ybuf);
    ff_ln_kernel<<<976, 128, 0, stream>>>(f1w + l * 256 * 128, f1b + l * 256,
                                          f2w + l * 128 * 256, f2b + l * 128,
                                          l2g + l * 128, l2b + l * 128, ybuf);
  }
  head_kernel<<<1, 256, 0, stream>>>(ybuf, fl, fc1w, fc1b, bn1g, bn1b,
                                     fc15w, fc15b, bn15g, bn15b,
                                     fc2w, fc2b, bn2g, bn2b, fcw, fcb, out);
}

// Round 2
// 274.970 us; speedup vs baseline: 2.6909x; 2.6909x over previous
//
#include <hip/hip_runtime.h>
#include <math.h>

#define BB 16
#define FF 60
#define NPTS 512
#define EMB 128
#define SS 61
#define EPSV 1e-5f

typedef __attribute__((ext_vector_type(8))) short bf16x8;
typedef __attribute__((ext_vector_type(4))) float f32x4;

__device__ __forceinline__ unsigned f2bf(float f){
  unsigned u = __float_as_uint(f);
  return (u + 0x7fffu + ((u >> 16) & 1u)) >> 16;
}

// ---------------- encoder: MFMA, transposed formulation, one wave per frame ----------------
// Layer2: D2[ch2][pt] = w2^T(A) * h1^T(B).  Layer3: D3[och][pt] = w3^T(A) * h2^T(B),
// where h2^T B-fragments are the layer2 D registers reinterpreted (A placed with the
// same (group,slot)->k map, so the hw k-permutation cancels).
__global__ __launch_bounds__(256, 1) void enc_kernel(
    const float* __restrict__ x,
    const float* __restrict__ ew1, const float* __restrict__ eb1,
    const float* __restrict__ ew2, const float* __restrict__ eb2,
    const float* __restrict__ ew3, const float* __restrict__ eb3,
    float* __restrict__ ymax)
{
  const int tid  = threadIdx.x;
  const int lane = tid & 63;
  const int wv   = tid >> 6;
  const int frame = blockIdx.x * 4 + wv;      // 0..959
  const int c = lane & 15;                    // D column: point slot / A row col
  const int g = lane >> 4;                    // lane group 0..3

  // ---- weight fragments (loaded once per wave, bf16) ----
  bf16x8 A2[8][2];   // w2^T: A[m=ch2=mt*16+c][k=ch1=ks*32+g*8+i]
#pragma unroll
  for (int mt = 0; mt < 8; mt++)
#pragma unroll
    for (int ks = 0; ks < 2; ks++) {
      bf16x8 a;
#pragma unroll
      for (int i = 0; i < 8; i++)
        a[i] = (short)f2bf(ew2[(ks * 32 + g * 8 + i) * 128 + mt * 16 + c]);
      A2[mt][ks] = a;
    }
  bf16x8 A3[8][4];   // w3^T: A[m=och=mt*16+c][k=ch2=ks*32+16*(i>>2)+4*g+(i&3)]
#pragma unroll
  for (int mt = 0; mt < 8; mt++)
#pragma unroll
    for (int ks = 0; ks < 4; ks++) {
      bf16x8 a;
#pragma unroll
      for (int i = 0; i < 8; i++)
        a[i] = (short)f2bf(ew3[(ks * 32 + 16 * (i >> 2) + 4 * g + (i & 3)) * 128 + mt * 16 + c]);
      A3[mt][ks] = a;
    }

  // layer2 bias, pre-indexed for the D layout (row = 4g+r)
  float b2r[8][4];
#pragma unroll
  for (int mt = 0; mt < 8; mt++)
#pragma unroll
    for (int r = 0; r < 4; r++) b2r[mt][r] = eb2[mt * 16 + 4 * g + r];

  // layer1 weights for this lane's 16 channels: ch = ks*32 + g*8 + i
  float w1a[2][8], w1b[2][8], w1c[2][8], b1l[2][8];
#pragma unroll
  for (int ks = 0; ks < 2; ks++)
#pragma unroll
    for (int i = 0; i < 8; i++) {
      const int ch = ks * 32 + g * 8 + i;
      w1a[ks][i] = ew1[ch];
      w1b[ks][i] = ew1[64 + ch];
      w1c[ks][i] = ew1[128 + ch];
      b1l[ks][i] = eb1[ch];
    }

  f32x4 pool[8];
#pragma unroll
  for (int mt = 0; mt < 8; mt++) pool[mt] = {-1e30f, -1e30f, -1e30f, -1e30f};

  const float* xf = x + (size_t)frame * NPTS * 3;
  float nx0, nx1, nx2;
  { const float* xp = xf + c * 3; nx0 = xp[0]; nx1 = xp[1]; nx2 = xp[2]; }

  for (int t = 0; t < 32; t++) {
    const float x0 = nx0, x1 = nx1, x2 = nx2;
    if (t < 31) {   // 1-deep prefetch of next 16-point group
      const float* xp = xf + ((t + 1) * 16 + c) * 3;
      nx0 = xp[0]; nx1 = xp[1]; nx2 = xp[2];
    }
    // layer1 -> B2 fragments (h1^T), only this lane's 16 channels
    bf16x8 B2[2];
#pragma unroll
    for (int ks = 0; ks < 2; ks++) {
      bf16x8 bfr;
#pragma unroll
      for (int i = 0; i < 8; i++) {
        float a = fmaf(x0, w1a[ks][i], fmaf(x1, w1b[ks][i], fmaf(x2, w1c[ks][i], b1l[ks][i])));
        bfr[i] = (short)f2bf(fmaxf(a, 0.f));
      }
      B2[ks] = bfr;
    }
    // layer2 MFMA
    f32x4 acc2[8];
#pragma unroll
    for (int mt = 0; mt < 8; mt++) {
      f32x4 a = {b2r[mt][0], b2r[mt][1], b2r[mt][2], b2r[mt][3]};
      a = __builtin_amdgcn_mfma_f32_16x16x32_bf16(A2[mt][0], B2[0], a, 0, 0, 0);
      a = __builtin_amdgcn_mfma_f32_16x16x32_bf16(A2[mt][1], B2[1], a, 0, 0, 0);
      acc2[mt] = a;
    }
    // relu + pack D2 registers into B3 fragments (h2^T) — same k-map as A3
    bf16x8 B3[4];
#pragma unroll
    for (int ks = 0; ks < 4; ks++) {
      bf16x8 bfr;
#pragma unroll
      for (int i = 0; i < 8; i++) {
        float v = acc2[2 * ks + (i >> 2)][i & 3];
        bfr[i] = (short)f2bf(fmaxf(v, 0.f));
      }
      B3[ks] = bfr;
    }
    // layer3 MFMA + running max-pool
#pragma unroll
    for (int mt = 0; mt < 8; mt++) {
      f32x4 a = {0.f, 0.f, 0.f, 0.f};
      a = __builtin_amdgcn_mfma_f32_16x16x32_bf16(A3[mt][0], B3[0], a, 0, 0, 0);
      a = __builtin_amdgcn_mfma_f32_16x16x32_bf16(A3[mt][1], B3[1], a, 0, 0, 0);
      a = __builtin_amdgcn_mfma_f32_16x16x32_bf16(A3[mt][2], B3[2], a, 0, 0, 0);
      a = __builtin_amdgcn_mfma_f32_16x16x32_bf16(A3[mt][3], B3[3], a, 0, 0, 0);
#pragma unroll
      for (int r = 0; r < 4; r++) pool[mt][r] = fmaxf(pool[mt][r], a[r]);
    }
  }

  // reduce over the 16 point-columns (lanes sharing the same group)
#pragma unroll
  for (int mt = 0; mt < 8; mt++)
#pragma unroll
    for (int r = 0; r < 4; r++) {
      float v = pool[mt][r];
      v = fmaxf(v, __shfl_xor(v, 1, 64));
      v = fmaxf(v, __shfl_xor(v, 2, 64));
      v = fmaxf(v, __shfl_xor(v, 4, 64));
      v = fmaxf(v, __shfl_xor(v, 8, 64));
      pool[mt][r] = v;
    }
  if (c == 0) {
#pragma unroll
    for (int mt = 0; mt < 8; mt++)
#pragma unroll
      for (int r = 0; r < 4; r++) {
        const int och = mt * 16 + 4 * g + r;
        ymax[(size_t)frame * 128 + och] = pool[mt][r] + eb3[och];  // bias after max (uniform over pts)
      }
  }
}

// ---------------- token assembly: cls + masked frame embeddings + pos enc ----------------
__global__ __launch_bounds__(128) void assemble_kernel(
    const float* __restrict__ ymax, const int* __restrict__ fl,
    const float* __restrict__ cls_token, const float* __restrict__ cls_pos,
    float* __restrict__ y)
{
  const int s = blockIdx.x;        // 0..975
  const int b = s / SS, t = s % SS;
  const int d = threadIdx.x;
  float v;
  if (t == 0) {
    v = cls_token[d] + cls_pos[d];
  } else {
    const int f = t - 1;
    float ym = 0.f;
    if (f < fl[b]) ym = ymax[(size_t)(b * FF + f) * 128 + d];
    float ang = (float)f * expf((float)(2 * (d >> 1)) * (-9.210340371976184f / 128.f));
    float pe = (d & 1) ? cosf(ang) : sinf(ang);
    v = ym + pe;
  }
  y[s * 128 + d] = v;
}

// ---------------- qkv projection ----------------
__global__ __launch_bounds__(128) void qkv_kernel(
    const float* __restrict__ y, const float* __restrict__ iw, const float* __restrict__ ib,
    float* __restrict__ qkv)
{
  __shared__ float ys[128];
  const int t = blockIdx.x, d = threadIdx.x;
  ys[d] = y[t * 128 + d];
  __syncthreads();
  for (int part = 0; part < 3; part++) {
    const int j = part * 128 + d;
    const float* wr = iw + j * 128;
    float acc = ib[j];
#pragma unroll 8
    for (int e = 0; e < 128; e++) acc = fmaf(ys[e], wr[e], acc);
    qkv[t * 384 + j] = acc;
  }
}

// ---------------- attention (one wave per (b,h)) ----------------
__global__ __launch_bounds__(64) void attn_kernel(
    const float* __restrict__ qkv, const int* __restrict__ fl,
    float* __restrict__ obuf)
{
  __shared__ float kx[SS][33];
  __shared__ float vx[SS][33];
  __shared__ float sc[64][64];
  const int b = blockIdx.x >> 2, h = blockIdx.x & 3;
  const int tid = threadIdx.x;
  for (int idx = tid; idx < SS * 32; idx += 64) {
    const int t = idx >> 5, d = idx & 31;
    const float* base = qkv + (size_t)(b * SS + t) * 384 + h * 32 + d;
    kx[t][d] = base[128];
    vx[t][d] = base[256];
  }
  __syncthreads();
  const int i = tid;
  if (i < SS) {
    float q[32];
    const float* qp = qkv + (size_t)(b * SS + i) * 384 + h * 32;
#pragma unroll
    for (int d = 0; d < 32; d++) q[d] = qp[d];
    const int f = fl[b];
    float m = -1e30f;
    for (int t = 0; t < SS; t++) {
      float s = 0.f;
#pragma unroll
      for (int d = 0; d < 32; d++) s = fmaf(q[d], kx[t][d], s);
      s *= 0.17677669529663687f;         // 1/sqrt(32)
      if (t > f) s += -1e9f;
      sc[i][t] = s;
      m = fmaxf(m, s);
    }
    float sum = 0.f;
    for (int t = 0; t < SS; t++) {
      float p = expf(sc[i][t] - m);
      sc[i][t] = p;
      sum += p;
    }
    const float inv = 1.f / sum;
    float o[32];
#pragma unroll
    for (int d = 0; d < 32; d++) o[d] = 0.f;
    for (int t = 0; t < SS; t++) {
      const float p = sc[i][t];
#pragma unroll
      for (int d = 0; d < 32; d++) o[d] = fmaf(p, vx[t][d], o[d]);
    }
    float* op = obuf + (size_t)(b * SS + i) * 128 + h * 32;
#pragma unroll
    for (int d = 0; d < 32; d++) op[d] = o[d] * inv;
  }
}

// ---------------- attention out-proj + residual + LN1 (in-place y) ----------------
__global__ __launch_bounds__(128) void proj_ln_kernel(
    const float* __restrict__ obuf, const float* __restrict__ ow, const float* __restrict__ ob,
    const float* __restrict__ g, const float* __restrict__ bb,
    float* __restrict__ y)
{
  __shared__ float os[128];
  __shared__ float rs[128];
  const int t = blockIdx.x, d = threadIdx.x;
  os[d] = obuf[t * 128 + d];
  __syncthreads();
  const float* wr = ow + d * 128;
  float acc = ob[d];
#pragma unroll 8
  for (int e = 0; e < 128; e++) acc = fmaf(os[e], wr[e], acc);
  const float r = y[t * 128 + d] + acc;
  rs[d] = r;
  __syncthreads();
  float s1 = 0.f, s2 = 0.f;
#pragma unroll 8
  for (int e = 0; e < 128; e++) { const float v = rs[e]; s1 += v; s2 = fmaf(v, v, s2); }
  const float mean = s1 * (1.f / 128.f);
  const float var = s2 * (1.f / 128.f) - mean * mean;
  const float inv = 1.f / sqrtf(var + EPSV);
  y[t * 128 + d] = (r - mean) * inv * g[d] + bb[d];
}

// ---------------- FF (128->256 relu ->128) + residual + LN2 (in-place y) ----------------
__global__ __launch_bounds__(128) void ff_ln_kernel(
    const float* __restrict__ w1, const float* __restrict__ b1,
    const float* __restrict__ w2, const float* __restrict__ b2,
    const float* __restrict__ g, const float* __restrict__ bb,
    float* __restrict__ y)
{
  __shared__ float ys[128];
  __shared__ float ffs[256];
  __shared__ float rs[128];
  const int t = blockIdx.x, d = threadIdx.x;
  ys[d] = y[t * 128 + d];
  __syncthreads();
  for (int rr = 0; rr < 2; rr++) {
    const int j = rr * 128 + d;
    const float* wr = w1 + j * 128;
    float acc = b1[j];
#pragma unroll 8
    for (int e = 0; e < 128; e++) acc = fmaf(ys[e], wr[e], acc);
    ffs[j] = fmaxf(acc, 0.f);
  }
  __syncthreads();
  const float* wr2 = w2 + d * 256;
  float acc = b2[d];
#pragma unroll 8
  for (int e = 0; e < 256; e++) acc = fmaf(ffs[e], wr2[e], acc);
  const float r = ys[d] + acc;
  rs[d] = r;
  __syncthreads();
  float s1 = 0.f, s2 = 0.f;
#pragma unroll 8
  for (int e = 0; e < 128; e++) { const float v = rs[e]; s1 += v; s2 = fmaf(v, v, s2); }
  const float mean = s1 * (1.f / 128.f);
  const float var = s2 * (1.f / 128.f) - mean * mean;
  const float inv = 1.f / sqrtf(var + EPSV);
  y[t * 128 + d] = (r - mean) * inv * g[d] + bb[d];
}

// ---------------- classifier head with live batch-norm (single block) ----------------
__global__ __launch_bounds__(256) void head_kernel(
    const float* __restrict__ y, const int* __restrict__ fl,
    const float* __restrict__ fc1w, const float* __restrict__ fc1b,
    const float* __restrict__ bn1g, const float* __restrict__ bn1b,
    const float* __restrict__ fc15w, const float* __restrict__ fc15b,
    const float* __restrict__ bn15g, const float* __restrict__ bn15b,
    const float* __restrict__ fc2w, const float* __restrict__ fc2b,
    const float* __restrict__ bn2g, const float* __restrict__ bn2b,
    const float* __restrict__ fcw, const float* __restrict__ fcb,
    float* __restrict__ out)
{
  __shared__ float zc[16 * 256];
  __shared__ float t1[16 * 128];
  __shared__ float t15[16 * 64];
  __shared__ float t2[16 * 32];
  const int tid = threadIdx.x;

  for (int idx = tid; idx < 16 * 256; idx += 256) {
    const int b = idx >> 8, d = idx & 255;
    zc[idx] = (d < 128) ? y[(size_t)(b * SS) * 128 + d]
                        : y[(size_t)(b * SS + fl[b]) * 128 + (d - 128)];
  }
  __syncthreads();

  for (int idx = tid; idx < 16 * 128; idx += 256) {
    const int b = idx >> 7, j = idx & 127;
    float a = fc1b[j];
    for (int k = 0; k < 256; k++) a = fmaf(zc[b * 256 + k], fc1w[k * 128 + j], a);
    t1[idx] = a;
  }
  __syncthreads();
  if (tid < 128) {
    const int j = tid;
    float s1 = 0.f, s2 = 0.f;
    for (int b = 0; b < 16; b++) { const float v = t1[b * 128 + j]; s1 += v; s2 = fmaf(v, v, s2); }
    const float m = s1 * (1.f / 16.f);
    const float var = s2 * (1.f / 16.f) - m * m;
    const float scl = bn1g[j] / sqrtf(var + EPSV);
    const float sh = bn1b[j] - m * scl;
    for (int b = 0; b < 16; b++) {
      const float v = t1[b * 128 + j] * scl + sh;
      t1[b * 128 + j] = (v > 0.f) ? v : 0.2f * v;
    }
  }
  __syncthreads();

  for (int idx = tid; idx < 16 * 64; idx += 256) {
    const int b = idx >> 6, j = idx & 63;
    float a = fc15b[j];
    for (int k = 0; k < 128; k++) a = fmaf(t1[b * 128 + k], fc15w[k * 64 + j], a);
    t15[idx] = a;
  }
  __syncthreads();
  if (tid < 64) {
    const int j = tid;
    float s1 = 0.f, s2 = 0.f;
    for (int b = 0; b < 16; b++) { const float v = t15[b * 64 + j]; s1 += v; s2 = fmaf(v, v, s2); }
    const float m = s1 * (1.f / 16.f);
    const float var = s2 * (1.f / 16.f) - m * m;
    const float scl = bn15g[j] / sqrtf(var + EPSV);
    const float sh = bn15b[j] - m * scl;
    for (int b = 0; b < 16; b++) {
      const float v = t15[b * 64 + j] * scl + sh;
      t15[b * 64 + j] = (v > 0.f) ? v : 0.2f * v;
    }
  }
  __syncthreads();

  for (int idx = tid; idx < 16 * 32; idx += 256) {
    const int b = idx >> 5, j = idx & 31;
    float a = fc2b[j];
    for (int k = 0; k < 64; k++) a = fmaf(t15[b * 64 + k], fc2w[k * 32 + j], a);
    t2[idx] = a;
  }
  __syncthreads();
  if (tid < 32) {
    const int j = tid;
    float s1 = 0.f, s2 = 0.f;
    for (int b = 0; b < 16; b++) { const float v = t2[b * 32 + j]; s1 += v; s2 = fmaf(v, v, s2); }
    const float m = s1 * (1.f / 16.f);
    const float var = s2 * (1.f / 16.f) - m * m;
    const float scl = bn2g[j] / sqrtf(var + EPSV);
    const float sh = bn2b[j] - m * scl;
    for (int b = 0; b < 16; b++) {
      const float v = t2[b * 32 + j] * scl + sh;
      t2[b * 32 + j] = (v > 0.f) ? v : 0.2f * v;
    }
  }
  __syncthreads();

  for (int idx = tid; idx < 16 * 27; idx += 256) {
    const int b = idx / 27, c = idx % 27;
    float a = fcb[c];
    for (int k = 0; k < 32; k++) a = fmaf(t2[b * 32 + k], fcw[k * 27 + c], a);
    out[b * 27 + c] = a;
  }
}

extern "C" void kernel_launch(void* const* d_in, const int* in_sizes, int n_in,
                              void* d_out, int out_size, void* d_ws, size_t ws_size,
                              hipStream_t stream)
{
  const float* x    = (const float*)d_in[0];
  const int*   fl   = (const int*)d_in[1];
  const float* ew1  = (const float*)d_in[2];  const float* eb1 = (const float*)d_in[3];
  const float* ew2  = (const float*)d_in[4];  const float* eb2 = (const float*)d_in[5];
  const float* ew3  = (const float*)d_in[6];  const float* eb3 = (const float*)d_in[7];
  const float* ctok = (const float*)d_in[8];  const float* cpos = (const float*)d_in[9];
  const float* in_w = (const float*)d_in[10]; const float* in_b = (const float*)d_in[11];
  const float* ow   = (const float*)d_in[12]; const float* ob   = (const float*)d_in[13];
  const float* l1g  = (const float*)d_in[14]; const float* l1b  = (const float*)d_in[15];
  const float* f1w  = (const float*)d_in[16]; const float* f1b  = (const float*)d_in[17];
  const float* f2w  = (const float*)d_in[18]; const float* f2b  = (const float*)d_in[19];
  const float* l2g  = (const float*)d_in[20]; const float* l2b  = (const float*)d_in[21];
  const float* fc1w = (const float*)d_in[22]; const float* fc1b = (const float*)d_in[23];
  const float* bn1g = (const float*)d_in[24]; const float* bn1b = (const float*)d_in[25];
  const float* fc15w= (const float*)d_in[26]; const float* fc15b= (const float*)d_in[27];
  const float* bn15g= (const float*)d_in[28]; const float* bn15b= (const float*)d_in[29];
  const float* fc2w = (const float*)d_in[30]; const float* fc2b = (const float*)d_in[31];
  const float* bn2g = (const float*)d_in[32]; const float* bn2b = (const float*)d_in[33];
  const float* fcw  = (const float*)d_in[34]; const float* fcb  = (const float*)d_in[35];
  float* out = (float*)d_out;

  char* w = (char*)d_ws;
  float* ymax = (float*)w;                                           // 960*128*4 = 491520
  float* ybuf = (float*)(w + 491520);                                // 976*128*4 = 499712
  float* qkvb = (float*)(w + 491520 + 499712);                       // 976*384*4 = 1499136
  float* obuf = (float*)(w + 491520 + 499712 + 1499136);             // 499712

  enc_kernel<<<240, 256, 0, stream>>>(x, ew1, eb1, ew2, eb2, ew3, eb3, ymax);
  assemble_kernel<<<976, 128, 0, stream>>>(ymax, fl, ctok, cpos, ybuf);
  for (int l = 0; l < 2; l++) {
    qkv_kernel<<<976, 128, 0, stream>>>(ybuf, in_w + l * 384 * 128, in_b + l * 384, qkvb);
    attn_kernel<<<64, 64, 0, stream>>>(qkvb, fl, obuf);
    proj_ln_kernel<<<976, 128, 0, stream>>>(obuf, ow + l * 128 * 128, ob + l * 128,
                                            l1g + l * 128, l1b + l * 128, ybuf);
    ff_ln_kernel<<<976, 128, 0, stream>>>(f1w + l * 256 * 128, f1b + l * 256,
                                          f2w + l * 128 * 256, f2b + l * 128,
                                          l2g + l * 128, l2b + l * 128, ybuf);
  }
  head_kernel<<<1, 256, 0, stream>>>(ybuf, fl, fc1w, fc1b, bn1g, bn1b,
                                     fc15w, fc15b, bn15g, bn15b,
                                     fc2w, fc2b, bn2g, bn2b, fcw, fcb, out);
}

// Round 3
// 169.007 us; speedup vs baseline: 4.3780x; 1.6270x over previous
//
#include <hip/hip_runtime.h>
#include <math.h>

#define SS 61
#define EPSV 1e-5f

typedef __attribute__((ext_vector_type(8))) short bf16x8;
typedef __attribute__((ext_vector_type(4))) short s16x4;
typedef __attribute__((ext_vector_type(4))) float f32x4;

__device__ __forceinline__ unsigned short f2bfu(float f){
  unsigned u = __float_as_uint(f);
  return (unsigned short)((u + 0x7fffu + ((u >> 16) & 1u)) >> 16);
}
__device__ __forceinline__ bf16x8 pack8(f32x4 lo, f32x4 hi){
  bf16x8 r;
  r[0]=(short)f2bfu(lo[0]); r[1]=(short)f2bfu(lo[1]); r[2]=(short)f2bfu(lo[2]); r[3]=(short)f2bfu(lo[3]);
  r[4]=(short)f2bfu(hi[0]); r[5]=(short)f2bfu(hi[1]); r[6]=(short)f2bfu(hi[2]); r[7]=(short)f2bfu(hi[3]);
  return r;
}
__device__ __forceinline__ s16x4 pack4(f32x4 v){
  s16x4 r;
  r[0]=(short)f2bfu(v[0]); r[1]=(short)f2bfu(v[1]); r[2]=(short)f2bfu(v[2]); r[3]=(short)f2bfu(v[3]);
  return r;
}
// swizzled index helpers (granule >= vector width, bijective per row)
#define YI(t,d) (((t)<<7) + ((d) ^ (((t)&7)<<2)))
#define OI(t,e) (((t)<<7) + ((e) ^ (((t)&7)<<2)))
#define FI(t,e) (((t)<<8) + ((e) ^ (((t)&7)<<2)))
#define VI(k,d) (((k)<<5) + ((d) ^ (((k)&7)<<2)))

__device__ __forceinline__ bf16x8 ldW(const float* Wrow, int e0){
  f32x4 lo = *(const f32x4*)(Wrow + e0);
  f32x4 hi = *(const f32x4*)(Wrow + e0 + 16);
  return pack8(lo, hi);
}

// ---------------- encoder: MFMA, 4 waves per frame (8 point-groups each) ----------------
__global__ __launch_bounds__(256, 1) void enc_kernel(
    const float* __restrict__ x,
    const float* __restrict__ ew1, const float* __restrict__ eb1,
    const float* __restrict__ ew2, const float* __restrict__ eb2,
    const float* __restrict__ ew3, const float* __restrict__ eb3,
    float* __restrict__ ymax)
{
  __shared__ float pmerge[4][128];
  const int tid  = threadIdx.x;
  const int lane = tid & 63;
  const int wv   = tid >> 6;
  const int frame = blockIdx.x;               // 0..959
  const int c = lane & 15;
  const int g = lane >> 4;

  bf16x8 A2[8][2];   // w2^T: A[m=ch2=mt*16+c][k=ch1=ks*32+g*8+i]
#pragma unroll
  for (int mt = 0; mt < 8; mt++)
#pragma unroll
    for (int ks = 0; ks < 2; ks++) {
      bf16x8 a;
#pragma unroll
      for (int i = 0; i < 8; i++)
        a[i] = (short)f2bfu(ew2[(ks * 32 + g * 8 + i) * 128 + mt * 16 + c]);
      A2[mt][ks] = a;
    }
  bf16x8 A3[8][4];   // w3^T: A[m=och][k=ch2=ks*32+16*(i>>2)+4*g+(i&3)]
#pragma unroll
  for (int mt = 0; mt < 8; mt++)
#pragma unroll
    for (int ks = 0; ks < 4; ks++) {
      bf16x8 a;
#pragma unroll
      for (int i = 0; i < 8; i++)
        a[i] = (short)f2bfu(ew3[(ks * 32 + 16 * (i >> 2) + 4 * g + (i & 3)) * 128 + mt * 16 + c]);
      A3[mt][ks] = a;
    }
  float b2r[8][4];
#pragma unroll
  for (int mt = 0; mt < 8; mt++)
#pragma unroll
    for (int r = 0; r < 4; r++) b2r[mt][r] = eb2[mt * 16 + 4 * g + r];

  float w1a[2][8], w1b[2][8], w1c[2][8], b1l[2][8];
#pragma unroll
  for (int ks = 0; ks < 2; ks++)
#pragma unroll
    for (int i = 0; i < 8; i++) {
      const int ch = ks * 32 + g * 8 + i;
      w1a[ks][i] = ew1[ch];
      w1b[ks][i] = ew1[64 + ch];
      w1c[ks][i] = ew1[128 + ch];
      b1l[ks][i] = eb1[ch];
    }

  f32x4 pool[8];
#pragma unroll
  for (int mt = 0; mt < 8; mt++) pool[mt] = {-1e30f, -1e30f, -1e30f, -1e30f};

  const float* xf = x + (size_t)frame * 512 * 3;
  const int t0 = wv * 8;
  float nx0, nx1, nx2;
  { const float* xp = xf + (t0 * 16 + c) * 3; nx0 = xp[0]; nx1 = xp[1]; nx2 = xp[2]; }

  for (int t = t0; t < t0 + 8; t++) {
    const float x0 = nx0, x1 = nx1, x2 = nx2;
    if (t < t0 + 7) {
      const float* xp = xf + ((t + 1) * 16 + c) * 3;
      nx0 = xp[0]; nx1 = xp[1]; nx2 = xp[2];
    }
    bf16x8 B2[2];
#pragma unroll
    for (int ks = 0; ks < 2; ks++) {
      bf16x8 bfr;
#pragma unroll
      for (int i = 0; i < 8; i++) {
        float a = fmaf(x0, w1a[ks][i], fmaf(x1, w1b[ks][i], fmaf(x2, w1c[ks][i], b1l[ks][i])));
        bfr[i] = (short)f2bfu(fmaxf(a, 0.f));
      }
      B2[ks] = bfr;
    }
    f32x4 acc2[8];
#pragma unroll
    for (int mt = 0; mt < 8; mt++) {
      f32x4 a = {b2r[mt][0], b2r[mt][1], b2r[mt][2], b2r[mt][3]};
      a = __builtin_amdgcn_mfma_f32_16x16x32_bf16(A2[mt][0], B2[0], a, 0, 0, 0);
      a = __builtin_amdgcn_mfma_f32_16x16x32_bf16(A2[mt][1], B2[1], a, 0, 0, 0);
      acc2[mt] = a;
    }
    bf16x8 B3[4];
#pragma unroll
    for (int ks = 0; ks < 4; ks++) {
      bf16x8 bfr;
#pragma unroll
      for (int i = 0; i < 8; i++) {
        float v = acc2[2 * ks + (i >> 2)][i & 3];
        bfr[i] = (short)f2bfu(fmaxf(v, 0.f));
      }
      B3[ks] = bfr;
    }
#pragma unroll
    for (int mt = 0; mt < 8; mt++) {
      f32x4 a = {0.f, 0.f, 0.f, 0.f};
      a = __builtin_amdgcn_mfma_f32_16x16x32_bf16(A3[mt][0], B3[0], a, 0, 0, 0);
      a = __builtin_amdgcn_mfma_f32_16x16x32_bf16(A3[mt][1], B3[1], a, 0, 0, 0);
      a = __builtin_amdgcn_mfma_f32_16x16x32_bf16(A3[mt][2], B3[2], a, 0, 0, 0);
      a = __builtin_amdgcn_mfma_f32_16x16x32_bf16(A3[mt][3], B3[3], a, 0, 0, 0);
#pragma unroll
      for (int r = 0; r < 4; r++) pool[mt][r] = fmaxf(pool[mt][r], a[r]);
    }
  }

#pragma unroll
  for (int mt = 0; mt < 8; mt++)
#pragma unroll
    for (int r = 0; r < 4; r++) {
      float v = pool[mt][r];
      v = fmaxf(v, __shfl_xor(v, 1, 64));
      v = fmaxf(v, __shfl_xor(v, 2, 64));
      v = fmaxf(v, __shfl_xor(v, 4, 64));
      v = fmaxf(v, __shfl_xor(v, 8, 64));
      pool[mt][r] = v;
    }
  if (c == 0) {
#pragma unroll
    for (int mt = 0; mt < 8; mt++)
#pragma unroll
      for (int r = 0; r < 4; r++)
        pmerge[wv][mt * 16 + 4 * g + r] = pool[mt][r];
  }
  __syncthreads();
  if (tid < 128) {
    float v = fmaxf(fmaxf(pmerge[0][tid], pmerge[1][tid]),
                    fmaxf(pmerge[2][tid], pmerge[3][tid]));
    ymax[(size_t)frame * 128 + tid] = v + eb3[tid];
  }
}

// ---------------- fused transformer: one block per batch, one head per wave ----------------
__global__ __launch_bounds__(256, 1) void xformer_kernel(
    const float* __restrict__ ymax, const int* __restrict__ fl,
    const float* __restrict__ ctok, const float* __restrict__ cpos,
    const float* __restrict__ in_w, const float* __restrict__ in_b,
    const float* __restrict__ ow, const float* __restrict__ ob,
    const float* __restrict__ l1g, const float* __restrict__ l1b,
    const float* __restrict__ f1w, const float* __restrict__ f1b,
    const float* __restrict__ f2w, const float* __restrict__ f2b,
    const float* __restrict__ l2g, const float* __restrict__ l2b,
    float* __restrict__ zbuf)
{
  __shared__ __align__(16) float ylds[64 * 128];          // 32 KB, swizzled f32
  __shared__ __align__(16) unsigned short ubuf[64 * 256]; // 32 KB: O[0..8191] V[8192..] / ffs
  const int b = blockIdx.x, tid = threadIdx.x;
  const int w = tid >> 6, lane = tid & 63, c = lane & 15, g = lane >> 4;
  const int flb = fl[b];
  const float scl = 0.17677669529663687f;

  // ---- assemble y: cls + masked frame embeddings + positional encoding ----
  for (int it = 0; it < 32; it++) {
    int idx = it * 256 + tid;
    int t = idx >> 7, d = idx & 127;
    float v;
    if (t == 0) v = ctok[d] + cpos[d];
    else if (t <= 60) {
      int f = t - 1;
      float ym = (f < flb) ? ymax[(size_t)(b * 60 + f) * 128 + d] : 0.f;
      float dv = __expf((float)(d & ~1) * (-0.07195578416f));
      float ang = (float)f * dv;
      v = ym + ((d & 1) ? __cosf(ang) : __sinf(ang));
    } else v = 0.f;
    ylds[YI(t, d)] = v;
  }
  __syncthreads();

  for (int l = 0; l < 2; l++) {
    // ---------- qkvT GEMM: wave w computes its head's q,k,v channels ----------
    f32x4 Qd[2][4], Kd[2][4], Vd[2][4];
    {
      bf16x8 yB[4][4];
#pragma unroll
      for (int nt = 0; nt < 4; nt++)
#pragma unroll
        for (int ks = 0; ks < 4; ks++) {
          f32x4 lo = *(const f32x4*)&ylds[YI(16 * nt + c, 32 * ks + 4 * g)];
          f32x4 hi = *(const f32x4*)&ylds[YI(16 * nt + c, 32 * ks + 16 + 4 * g)];
          yB[nt][ks] = pack8(lo, hi);
        }
      const float* W  = in_w + (size_t)l * 384 * 128;
      const float* Wb = in_b + l * 384;
#pragma unroll
      for (int p = 0; p < 3; p++)
#pragma unroll
        for (int dt = 0; dt < 2; dt++) {
          const int j0 = p * 128 + 32 * w + 16 * dt;
          bf16x8 Af[4];
#pragma unroll
          for (int ks = 0; ks < 4; ks++) Af[ks] = ldW(W + (size_t)(j0 + c) * 128, 32 * ks + 4 * g);
          f32x4 bias = *(const f32x4*)(Wb + j0 + 4 * g);
          f32x4 acc[4];
#pragma unroll
          for (int nt = 0; nt < 4; nt++) acc[nt] = bias;
#pragma unroll
          for (int ks = 0; ks < 4; ks++)
#pragma unroll
            for (int nt = 0; nt < 4; nt++)
              acc[nt] = __builtin_amdgcn_mfma_f32_16x16x32_bf16(Af[ks], yB[nt][ks], acc[nt], 0, 0, 0);
#pragma unroll
          for (int nt = 0; nt < 4; nt++) {
            if (p == 0) Qd[dt][nt] = acc[nt];
            else if (p == 1) Kd[dt][nt] = acc[nt];
            else Vd[dt][nt] = acc[nt];
          }
        }
    }

    // ---------- attention (head h = w) ----------
    {
      unsigned short* vb = ubuf + 8192 + w * 2048;   // head-private V^ region
#pragma unroll
      for (int dt = 0; dt < 2; dt++)
#pragma unroll
        for (int nt = 0; nt < 4; nt++)
          *(s16x4*)&vb[VI(16 * nt + c, 16 * dt + 4 * g)] = pack4(Vd[dt][nt]);

      bf16x8 Bq[4], Ak[4];
#pragma unroll
      for (int qt = 0; qt < 4; qt++) {
        bf16x8 r;
#pragma unroll
        for (int i = 0; i < 8; i++) r[i] = (short)f2bfu(scl * Qd[i >> 2][qt][i & 3]);
        Bq[qt] = r;
      }
#pragma unroll
      for (int kt = 0; kt < 4; kt++) {
        bf16x8 r;
#pragma unroll
        for (int i = 0; i < 8; i++) r[i] = (short)f2bfu(Kd[i >> 2][kt][i & 3]);
        Ak[kt] = r;
      }
      f32x4 St[4][4];          // S^T tiles: [kpos-tile][q-tile]
#pragma unroll
      for (int kt = 0; kt < 4; kt++)
#pragma unroll
        for (int qt = 0; qt < 4; qt++) {
          f32x4 z = {0.f, 0.f, 0.f, 0.f};
          St[kt][qt] = __builtin_amdgcn_mfma_f32_16x16x32_bf16(Ak[kt], Bq[qt], z, 0, 0, 0);
        }
      // softmax over kpos (mask kpos > flb); lane holds kpos = 16*kt+4*g+r at q = 16*qt+c
#pragma unroll
      for (int qt = 0; qt < 4; qt++) {
        float m = -1e30f;
#pragma unroll
        for (int kt = 0; kt < 4; kt++)
#pragma unroll
          for (int r = 0; r < 4; r++) {
            const int kp = 16 * kt + 4 * g + r;
            float s = St[kt][qt][r];
            s = (kp > flb) ? -1e30f : s;
            St[kt][qt][r] = s;
            m = fmaxf(m, s);
          }
        m = fmaxf(m, __shfl_xor(m, 16, 64));
        m = fmaxf(m, __shfl_xor(m, 32, 64));
        float sum = 0.f;
#pragma unroll
        for (int kt = 0; kt < 4; kt++)
#pragma unroll
          for (int r = 0; r < 4; r++) {
            float p = __expf(St[kt][qt][r] - m);
            St[kt][qt][r] = p;
            sum += p;
          }
        sum += __shfl_xor(sum, 16, 64);
        sum += __shfl_xor(sum, 32, 64);
        const float inv = 1.f / sum;
#pragma unroll
        for (int kt = 0; kt < 4; kt++)
#pragma unroll
          for (int r = 0; r < 4; r++) St[kt][qt][r] *= inv;
      }
      // P^T -> B-frags; V^T -> A-frags (same k-map sigma, permutation cancels)
      bf16x8 Bp[4][2];
#pragma unroll
      for (int qt = 0; qt < 4; qt++)
#pragma unroll
        for (int ks = 0; ks < 2; ks++) {
          bf16x8 r;
#pragma unroll
          for (int i = 0; i < 8; i++) r[i] = (short)f2bfu(St[2 * ks + (i >> 2)][qt][i & 3]);
          Bp[qt][ks] = r;
        }
      bf16x8 Av[2][2];
#pragma unroll
      for (int dt = 0; dt < 2; dt++)
#pragma unroll
        for (int ks = 0; ks < 2; ks++) {
          bf16x8 r;
#pragma unroll
          for (int i = 0; i < 8; i++) {
            const int kp = 32 * ks + 16 * (i >> 2) + 4 * g + (i & 3);
            r[i] = (short)vb[VI(kp, 16 * dt + c)];
          }
          Av[dt][ks] = r;
        }
#pragma unroll
      for (int dt = 0; dt < 2; dt++)
#pragma unroll
        for (int qt = 0; qt < 4; qt++) {
          f32x4 z = {0.f, 0.f, 0.f, 0.f};
          z = __builtin_amdgcn_mfma_f32_16x16x32_bf16(Av[dt][0], Bp[qt][0], z, 0, 0, 0);
          z = __builtin_amdgcn_mfma_f32_16x16x32_bf16(Av[dt][1], Bp[qt][1], z, 0, 0, 0);
          *(s16x4*)&ubuf[OI(16 * qt + c, 32 * w + 16 * dt + 4 * g)] = pack4(z);
        }
    }
    __syncthreads();

    // ---------- projT + residual ----------
    {
      bf16x8 Bo[4][4];
#pragma unroll
      for (int nt = 0; nt < 4; nt++)
#pragma unroll
        for (int ks = 0; ks < 4; ks++) {
          s16x4 lo = *(const s16x4*)&ubuf[OI(16 * nt + c, 32 * ks + 4 * g)];
          s16x4 hi = *(const s16x4*)&ubuf[OI(16 * nt + c, 32 * ks + 16 + 4 * g)];
          Bo[nt][ks] = __builtin_shufflevector(lo, hi, 0, 1, 2, 3, 4, 5, 6, 7);
        }
      const float* Wo  = ow + (size_t)l * 128 * 128;
      const float* Wob = ob + l * 128;
#pragma unroll
      for (int dt = 0; dt < 2; dt++) {
        const int j0 = 32 * w + 16 * dt;
        bf16x8 Af[4];
#pragma unroll
        for (int ks = 0; ks < 4; ks++) Af[ks] = ldW(Wo + (size_t)(j0 + c) * 128, 32 * ks + 4 * g);
        f32x4 bias = *(const f32x4*)(Wob + j0 + 4 * g);
        f32x4 acc[4];
#pragma unroll
        for (int nt = 0; nt < 4; nt++) acc[nt] = bias;
#pragma unroll
        for (int ks = 0; ks < 4; ks++)
#pragma unroll
          for (int nt = 0; nt < 4; nt++)
            acc[nt] = __builtin_amdgcn_mfma_f32_16x16x32_bf16(Af[ks], Bo[nt][ks], acc[nt], 0, 0, 0);
#pragma unroll
        for (int nt = 0; nt < 4; nt++) {
          float* yp = &ylds[YI(16 * nt + c, j0 + 4 * g)];
          *(f32x4*)yp = *(const f32x4*)yp + acc[nt];
        }
      }
    }
    __syncthreads();
    // ---------- LN1 ----------
    {
      const int t = 16 * w + (lane >> 2);
      const int ch = (lane & 3) * 32;
      f32x4 vv[8];
      float s1 = 0.f, s2 = 0.f;
#pragma unroll
      for (int k = 0; k < 8; k++) {
        vv[k] = *(const f32x4*)&ylds[YI(t, ch + 4 * k)];
#pragma unroll
        for (int r = 0; r < 4; r++) { s1 += vv[k][r]; s2 = fmaf(vv[k][r], vv[k][r], s2); }
      }
      s1 += __shfl_xor(s1, 1, 64); s1 += __shfl_xor(s1, 2, 64);
      s2 += __shfl_xor(s2, 1, 64); s2 += __shfl_xor(s2, 2, 64);
      const float mean = s1 * 0.0078125f;
      const float var  = s2 * 0.0078125f - mean * mean;
      const float inv  = rsqrtf(var + EPSV);
#pragma unroll
      for (int k = 0; k < 8; k++) {
        f32x4 gg = *(const f32x4*)(l1g + l * 128 + ch + 4 * k);
        f32x4 bb = *(const f32x4*)(l1b + l * 128 + ch + 4 * k);
        f32x4 o;
#pragma unroll
        for (int r = 0; r < 4; r++) o[r] = (vv[k][r] - mean) * inv * gg[r] + bb[r];
        *(f32x4*)&ylds[YI(t, ch + 4 * k)] = o;
      }
    }
    __syncthreads();

    // ---------- ff1T (relu) -> ffs ----------
    {
      bf16x8 yB[4][4];
#pragma unroll
      for (int nt = 0; nt < 4; nt++)
#pragma unroll
        for (int ks = 0; ks < 4; ks++) {
          f32x4 lo = *(const f32x4*)&ylds[YI(16 * nt + c, 32 * ks + 4 * g)];
          f32x4 hi = *(const f32x4*)&ylds[YI(16 * nt + c, 32 * ks + 16 + 4 * g)];
          yB[nt][ks] = pack8(lo, hi);
        }
      const float* W1 = f1w + (size_t)l * 256 * 128;
#pragma unroll
      for (int dt = 0; dt < 4; dt++) {
        const int j0 = 64 * w + 16 * dt;
        bf16x8 Af[4];
#pragma unroll
        for (int ks = 0; ks < 4; ks++) Af[ks] = ldW(W1 + (size_t)(j0 + c) * 128, 32 * ks + 4 * g);
        f32x4 bias = *(const f32x4*)(f1b + l * 256 + j0 + 4 * g);
        f32x4 acc[4];
#pragma unroll
        for (int nt = 0; nt < 4; nt++) acc[nt] = bias;
#pragma unroll
        for (int ks = 0; ks < 4; ks++)
#pragma unroll
          for (int nt = 0; nt < 4; nt++)
            acc[nt] = __builtin_amdgcn_mfma_f32_16x16x32_bf16(Af[ks], yB[nt][ks], acc[nt], 0, 0, 0);
#pragma unroll
        for (int nt = 0; nt < 4; nt++) {
          f32x4 rl;
#pragma unroll
          for (int r = 0; r < 4; r++) rl[r] = fmaxf(acc[nt][r], 0.f);
          *(s16x4*)&ubuf[FI(16 * nt + c, j0 + 4 * g)] = pack4(rl);
        }
      }
    }
    __syncthreads();
    // ---------- ff2T + residual ----------
    {
      const float* W2 = f2w + (size_t)l * 128 * 256;
      f32x4 acc2[2][4];
#pragma unroll
      for (int dt = 0; dt < 2; dt++) {
        f32x4 bias = *(const f32x4*)(f2b + l * 128 + 32 * w + 16 * dt + 4 * g);
#pragma unroll
        for (int nt = 0; nt < 4; nt++) acc2[dt][nt] = bias;
      }
#pragma unroll
      for (int ks = 0; ks < 8; ks++) {
        bf16x8 Bf[4];
#pragma unroll
        for (int nt = 0; nt < 4; nt++) {
          s16x4 lo = *(const s16x4*)&ubuf[FI(16 * nt + c, 32 * ks + 4 * g)];
          s16x4 hi = *(const s16x4*)&ubuf[FI(16 * nt + c, 32 * ks + 16 + 4 * g)];
          Bf[nt] = __builtin_shufflevector(lo, hi, 0, 1, 2, 3, 4, 5, 6, 7);
        }
#pragma unroll
        for (int dt = 0; dt < 2; dt++) {
          bf16x8 Af = ldW(W2 + (size_t)(32 * w + 16 * dt + c) * 256, 32 * ks + 4 * g);
#pragma unroll
          for (int nt = 0; nt < 4; nt++)
            acc2[dt][nt] = __builtin_amdgcn_mfma_f32_16x16x32_bf16(Af, Bf[nt], acc2[dt][nt], 0, 0, 0);
        }
      }
#pragma unroll
      for (int dt = 0; dt < 2; dt++)
#pragma unroll
        for (int nt = 0; nt < 4; nt++) {
          float* yp = &ylds[YI(16 * nt + c, 32 * w + 16 * dt + 4 * g)];
          *(f32x4*)yp = *(const f32x4*)yp + acc2[dt][nt];
        }
    }
    __syncthreads();
    // ---------- LN2 ----------
    {
      const int t = 16 * w + (lane >> 2);
      const int ch = (lane & 3) * 32;
      f32x4 vv[8];
      float s1 = 0.f, s2 = 0.f;
#pragma unroll
      for (int k = 0; k < 8; k++) {
        vv[k] = *(const f32x4*)&ylds[YI(t, ch + 4 * k)];
#pragma unroll
        for (int r = 0; r < 4; r++) { s1 += vv[k][r]; s2 = fmaf(vv[k][r], vv[k][r], s2); }
      }
      s1 += __shfl_xor(s1, 1, 64); s1 += __shfl_xor(s1, 2, 64);
      s2 += __shfl_xor(s2, 1, 64); s2 += __shfl_xor(s2, 2, 64);
      const float mean = s1 * 0.0078125f;
      const float var  = s2 * 0.0078125f - mean * mean;
      const float inv  = rsqrtf(var + EPSV);
#pragma unroll
      for (int k = 0; k < 8; k++) {
        f32x4 gg = *(const f32x4*)(l2g + l * 128 + ch + 4 * k);
        f32x4 bb = *(const f32x4*)(l2b + l * 128 + ch + 4 * k);
        f32x4 o;
#pragma unroll
        for (int r = 0; r < 4; r++) o[r] = (vv[k][r] - mean) * inv * gg[r] + bb[r];
        *(f32x4*)&ylds[YI(t, ch + 4 * k)] = o;
      }
    }
    __syncthreads();
  }

  // ---- emit classifier inputs: [cls row, frame_length row] ----
  if (tid < 128) zbuf[b * 256 + tid] = ylds[YI(0, tid)];
  else           zbuf[b * 256 + tid] = ylds[YI(flb, tid - 128)];
}

// ---------------- classifier head with live batch-norm (single block) ----------------
__global__ __launch_bounds__(256) void head_kernel(
    const float* __restrict__ zbuf,
    const float* __restrict__ fc1w, const float* __restrict__ fc1b,
    const float* __restrict__ bn1g, const float* __restrict__ bn1b,
    const float* __restrict__ fc15w, const float* __restrict__ fc15b,
    const float* __restrict__ bn15g, const float* __restrict__ bn15b,
    const float* __restrict__ fc2w, const float* __restrict__ fc2b,
    const float* __restrict__ bn2g, const float* __restrict__ bn2b,
    const float* __restrict__ fcw, const float* __restrict__ fcb,
    float* __restrict__ out)
{
  __shared__ float zc[16 * 256];
  __shared__ float t1[16 * 128];
  __shared__ float t15[16 * 64];
  __shared__ float t2[16 * 32];
  const int tid = threadIdx.x;

  for (int idx = tid; idx < 16 * 256; idx += 256) zc[idx] = zbuf[idx];
  __syncthreads();

  for (int idx = tid; idx < 16 * 128; idx += 256) {
    const int b = idx >> 7, j = idx & 127;
    float a = fc1b[j];
    for (int k = 0; k < 256; k++) a = fmaf(zc[b * 256 + k], fc1w[k * 128 + j], a);
    t1[idx] = a;
  }
  __syncthreads();
  if (tid < 128) {
    const int j = tid;
    float s1 = 0.f, s2 = 0.f;
    for (int b = 0; b < 16; b++) { const float v = t1[b * 128 + j]; s1 += v; s2 = fmaf(v, v, s2); }
    const float m = s1 * (1.f / 16.f);
    const float var = s2 * (1.f / 16.f) - m * m;
    const float scl = bn1g[j] / sqrtf(var + EPSV);
    const float sh = bn1b[j] - m * scl;
    for (int b = 0; b < 16; b++) {
      const float v = t1[b * 128 + j] * scl + sh;
      t1[b * 128 + j] = (v > 0.f) ? v : 0.2f * v;
    }
  }
  __syncthreads();

  for (int idx = tid; idx < 16 * 64; idx += 256) {
    const int b = idx >> 6, j = idx & 63;
    float a = fc15b[j];
    for (int k = 0; k < 128; k++) a = fmaf(t1[b * 128 + k], fc15w[k * 64 + j], a);
    t15[idx] = a;
  }
  __syncthreads();
  if (tid < 64) {
    const int j = tid;
    float s1 = 0.f, s2 = 0.f;
    for (int b = 0; b < 16; b++) { const float v = t15[b * 64 + j]; s1 += v; s2 = fmaf(v, v, s2); }
    const float m = s1 * (1.f / 16.f);
    const float var = s2 * (1.f / 16.f) - m * m;
    const float scl = bn15g[j] / sqrtf(var + EPSV);
    const float sh = bn15b[j] - m * scl;
    for (int b = 0; b < 16; b++) {
      const float v = t15[b * 64 + j] * scl + sh;
      t15[b * 64 + j] = (v > 0.f) ? v : 0.2f * v;
    }
  }
  __syncthreads();

  for (int idx = tid; idx < 16 * 32; idx += 256) {
    const int b = idx >> 5, j = idx & 31;
    float a = fc2b[j];
    for (int k = 0; k < 64; k++) a = fmaf(t15[b * 64 + k], fc2w[k * 32 + j], a);
    t2[idx] = a;
  }
  __syncthreads();
  if (tid < 32) {
    const int j = tid;
    float s1 = 0.f, s2 = 0.f;
    for (int b = 0; b < 16; b++) { const float v = t2[b * 32 + j]; s1 += v; s2 = fmaf(v, v, s2); }
    const float m = s1 * (1.f / 16.f);
    const float var = s2 * (1.f / 16.f) - m * m;
    const float scl = bn2g[j] / sqrtf(var + EPSV);
    const float sh = bn2b[j] - m * scl;
    for (int b = 0; b < 16; b++) {
      const float v = t2[b * 32 + j] * scl + sh;
      t2[b * 32 + j] = (v > 0.f) ? v : 0.2f * v;
    }
  }
  __syncthreads();

  for (int idx = tid; idx < 16 * 27; idx += 256) {
    const int b = idx / 27, cc = idx % 27;
    float a = fcb[cc];
    for (int k = 0; k < 32; k++) a = fmaf(t2[b * 32 + k], fcw[k * 27 + cc], a);
    out[b * 27 + cc] = a;
  }
}

extern "C" void kernel_launch(void* const* d_in, const int* in_sizes, int n_in,
                              void* d_out, int out_size, void* d_ws, size_t ws_size,
                              hipStream_t stream)
{
  const float* x    = (const float*)d_in[0];
  const int*   fl   = (const int*)d_in[1];
  const float* ew1  = (const float*)d_in[2];  const float* eb1 = (const float*)d_in[3];
  const float* ew2  = (const float*)d_in[4];  const float* eb2 = (const float*)d_in[5];
  const float* ew3  = (const float*)d_in[6];  const float* eb3 = (const float*)d_in[7];
  const float* ctok = (const float*)d_in[8];  const float* cpos = (const float*)d_in[9];
  const float* in_w = (const float*)d_in[10]; const float* in_b = (const float*)d_in[11];
  const float* ow   = (const float*)d_in[12]; const float* ob   = (const float*)d_in[13];
  const float* l1g  = (const float*)d_in[14]; const float* l1b  = (const float*)d_in[15];
  const float* f1w  = (const float*)d_in[16]; const float* f1b  = (const float*)d_in[17];
  const float* f2w  = (const float*)d_in[18]; const float* f2b  = (const float*)d_in[19];
  const float* l2g  = (const float*)d_in[20]; const float* l2b  = (const float*)d_in[21];
  const float* fc1w = (const float*)d_in[22]; const float* fc1b = (const float*)d_in[23];
  const float* bn1g = (const float*)d_in[24]; const float* bn1b = (const float*)d_in[25];
  const float* fc15w= (const float*)d_in[26]; const float* fc15b= (const float*)d_in[27];
  const float* bn15g= (const float*)d_in[28]; const float* bn15b= (const float*)d_in[29];
  const float* fc2w = (const float*)d_in[30]; const float* fc2b = (const float*)d_in[31];
  const float* bn2g = (const float*)d_in[32]; const float* bn2b = (const float*)d_in[33];
  const float* fcw  = (const float*)d_in[34]; const float* fcb  = (const float*)d_in[35];
  float* out = (float*)d_out;

  char* w = (char*)d_ws;
  float* ymax = (float*)w;                 // 960*128*4 = 491520 B
  float* zbuf = (float*)(w + 491520);      // 16*256*4  = 16384 B

  enc_kernel<<<960, 256, 0, stream>>>(x, ew1, eb1, ew2, eb2, ew3, eb3, ymax);
  xformer_kernel<<<16, 256, 0, stream>>>(ymax, fl, ctok, cpos, in_w, in_b, ow, ob,
                                         l1g, l1b, f1w, f1b, f2w, f2b, l2g, l2b, zbuf);
  head_kernel<<<1, 256, 0, stream>>>(zbuf, fc1w, fc1b, bn1g, bn1b,
                                     fc15w, fc15b, bn15g, bn15b,
                                     fc2w, fc2b, bn2g, bn2b, fcw, fcb, out);
}

// Round 4
// 118.548 us; speedup vs baseline: 6.2415x; 1.4256x over previous
//
#include <hip/hip_runtime.h>
#include <math.h>

#define SS 61
#define EPSV 1e-5f

typedef __attribute__((ext_vector_type(8))) short bf16x8;
typedef __attribute__((ext_vector_type(4))) short s16x4;
typedef __attribute__((ext_vector_type(4))) float f32x4;

__device__ __forceinline__ short f2bf(float f){
  return __builtin_bit_cast(short, (__bf16)f);
}
__device__ __forceinline__ bf16x8 pack8(f32x4 lo, f32x4 hi){
  bf16x8 r;
  r[0]=f2bf(lo[0]); r[1]=f2bf(lo[1]); r[2]=f2bf(lo[2]); r[3]=f2bf(lo[3]);
  r[4]=f2bf(hi[0]); r[5]=f2bf(hi[1]); r[6]=f2bf(hi[2]); r[7]=f2bf(hi[3]);
  return r;
}
__device__ __forceinline__ s16x4 pack4(f32x4 v){
  s16x4 r; r[0]=f2bf(v[0]); r[1]=f2bf(v[1]); r[2]=f2bf(v[2]); r[3]=f2bf(v[3]); return r;
}
// swizzled LDS index helpers (granule >= vector width, bijective per row)
#define YI(t,d) (((t)<<7) + ((d) ^ (((t)&7)<<2)))
#define OI(t,e) (((t)<<7) + ((e) ^ (((t)&7)<<2)))
#define FI(t,e) (((t)<<8) + ((e) ^ (((t)&7)<<2)))
#define VI(k,d) (((k)<<5) + ((d) ^ (((k)&7)<<2)))

// ================= weight prep: fp32 -> bf16 fragment-linear =================
// wbf layout (shorts):
//   [0)        enc A2: 16 frags (mt*2+ks), k-map 32ks+8g+i
//   [8192)     enc A3: 32 frags (mt*4+ks), k-map 32ks+16(i>>2)+4g+(i&3)
//   [24576 + l*131072) per layer:
//     qkv 96 frags (tq*4+ks) | ow 32 | f1 64 | f2 64 (t*8+ks, K=256)
__global__ __launch_bounds__(256) void prep_kernel(
    const float* __restrict__ ew2, const float* __restrict__ ew3,
    const float* __restrict__ in_w, const float* __restrict__ ow,
    const float* __restrict__ f1w, const float* __restrict__ f2w,
    unsigned short* __restrict__ wbf)
{
  int s = blockIdx.x * 256 + threadIdx.x;          // 0..286719
  int i = s & 7, lane = (s >> 3) & 63, frag = s >> 9;
  int c = lane & 15, g = lane >> 4;
  float v;
  if (frag < 16) {
    int mt = frag >> 1, ks = frag & 1;
    v = ew2[(ks * 32 + g * 8 + i) * 128 + mt * 16 + c];
  } else if (frag < 48) {
    int f = frag - 16; int mt = f >> 2, ks = f & 3;
    v = ew3[(ks * 32 + 16 * (i >> 2) + 4 * g + (i & 3)) * 128 + mt * 16 + c];
  } else {
    int f = frag - 48;
    int l = f >> 8; f &= 255;
    int k = 16 * (i >> 2) + 4 * g + (i & 3);
    if (f < 96) {
      int tq = f >> 2, ks = f & 3;
      v = in_w[(size_t)l * 49152 + (size_t)(16 * tq + c) * 128 + 32 * ks + k];
    } else if (f < 128) {
      int f3 = f - 96; int t = f3 >> 2, ks = f3 & 3;
      v = ow[(size_t)l * 16384 + (size_t)(16 * t + c) * 128 + 32 * ks + k];
    } else if (f < 192) {
      int f3 = f - 128; int t = f3 >> 2, ks = f3 & 3;
      v = f1w[(size_t)l * 32768 + (size_t)(16 * t + c) * 128 + 32 * ks + k];
    } else {
      int f3 = f - 192; int t = f3 >> 3, ks = f3 & 7;
      v = f2w[(size_t)l * 32768 + (size_t)(16 * t + c) * 256 + 32 * ks + k];
    }
  }
  wbf[s] = (unsigned short)f2bf(v);
}

// ================= encoder: MFMA, 4 waves/frame, coalesced prepped weights ===
__global__ __launch_bounds__(256, 1) void enc_kernel(
    const float* __restrict__ x,
    const float* __restrict__ ew1, const float* __restrict__ eb1,
    const float* __restrict__ eb2, const float* __restrict__ eb3,
    const unsigned short* __restrict__ wbf,
    float* __restrict__ ymax)
{
  __shared__ float pmerge[4][128];
  const int tid = threadIdx.x, lane = tid & 63, wv = tid >> 6;
  const int frame = blockIdx.x;                 // 0..959
  const int c = lane & 15, g = lane >> 4;
  const bf16x8* wf = (const bf16x8*)wbf;

  bf16x8 A2[8][2];
#pragma unroll
  for (int mt = 0; mt < 8; mt++)
#pragma unroll
    for (int ks = 0; ks < 2; ks++) A2[mt][ks] = wf[(mt * 2 + ks) * 64 + lane];
  bf16x8 A3[8][4];
#pragma unroll
  for (int mt = 0; mt < 8; mt++)
#pragma unroll
    for (int ks = 0; ks < 4; ks++) A3[mt][ks] = wf[(16 + mt * 4 + ks) * 64 + lane];
  f32x4 b2v[8];
#pragma unroll
  for (int mt = 0; mt < 8; mt++) b2v[mt] = *(const f32x4*)(eb2 + mt * 16 + 4 * g);

  float w1a[2][8], w1b[2][8], w1c[2][8], b1l[2][8];
#pragma unroll
  for (int ks = 0; ks < 2; ks++)
#pragma unroll
    for (int i = 0; i < 8; i++) {
      const int ch = ks * 32 + g * 8 + i;
      w1a[ks][i] = ew1[ch];
      w1b[ks][i] = ew1[64 + ch];
      w1c[ks][i] = ew1[128 + ch];
      b1l[ks][i] = eb1[ch];
    }

  f32x4 pool[8];
#pragma unroll
  for (int mt = 0; mt < 8; mt++) pool[mt] = {-1e30f, -1e30f, -1e30f, -1e30f};

  const float* xf = x + (size_t)frame * 512 * 3;
  const int t0 = wv * 8;
  float nx0, nx1, nx2;
  { const float* xp = xf + (t0 * 16 + c) * 3; nx0 = xp[0]; nx1 = xp[1]; nx2 = xp[2]; }

  for (int t = t0; t < t0 + 8; t++) {
    const float x0 = nx0, x1 = nx1, x2 = nx2;
    if (t < t0 + 7) {
      const float* xp = xf + ((t + 1) * 16 + c) * 3;
      nx0 = xp[0]; nx1 = xp[1]; nx2 = xp[2];
    }
    bf16x8 B2[2];
#pragma unroll
    for (int ks = 0; ks < 2; ks++) {
      bf16x8 bfr;
#pragma unroll
      for (int i = 0; i < 8; i++) {
        float a = fmaf(x0, w1a[ks][i], fmaf(x1, w1b[ks][i], fmaf(x2, w1c[ks][i], b1l[ks][i])));
        bfr[i] = f2bf(fmaxf(a, 0.f));
      }
      B2[ks] = bfr;
    }
    f32x4 acc2[8];
#pragma unroll
    for (int mt = 0; mt < 8; mt++) {
      f32x4 a = b2v[mt];
      a = __builtin_amdgcn_mfma_f32_16x16x32_bf16(A2[mt][0], B2[0], a, 0, 0, 0);
      a = __builtin_amdgcn_mfma_f32_16x16x32_bf16(A2[mt][1], B2[1], a, 0, 0, 0);
      acc2[mt] = a;
    }
    bf16x8 B3[4];
#pragma unroll
    for (int ks = 0; ks < 4; ks++) {
      bf16x8 bfr;
#pragma unroll
      for (int i = 0; i < 8; i++)
        bfr[i] = f2bf(fmaxf(acc2[2 * ks + (i >> 2)][i & 3], 0.f));
      B3[ks] = bfr;
    }
#pragma unroll
    for (int mt = 0; mt < 8; mt++) {
      f32x4 a = {0.f, 0.f, 0.f, 0.f};
      a = __builtin_amdgcn_mfma_f32_16x16x32_bf16(A3[mt][0], B3[0], a, 0, 0, 0);
      a = __builtin_amdgcn_mfma_f32_16x16x32_bf16(A3[mt][1], B3[1], a, 0, 0, 0);
      a = __builtin_amdgcn_mfma_f32_16x16x32_bf16(A3[mt][2], B3[2], a, 0, 0, 0);
      a = __builtin_amdgcn_mfma_f32_16x16x32_bf16(A3[mt][3], B3[3], a, 0, 0, 0);
#pragma unroll
      for (int r = 0; r < 4; r++) pool[mt][r] = fmaxf(pool[mt][r], a[r]);
    }
  }

#pragma unroll
  for (int mt = 0; mt < 8; mt++)
#pragma unroll
    for (int r = 0; r < 4; r++) {
      float v = pool[mt][r];
      v = fmaxf(v, __shfl_xor(v, 1, 64));
      v = fmaxf(v, __shfl_xor(v, 2, 64));
      v = fmaxf(v, __shfl_xor(v, 4, 64));
      v = fmaxf(v, __shfl_xor(v, 8, 64));
      pool[mt][r] = v;
    }
  if (c == 0) {
#pragma unroll
    for (int mt = 0; mt < 8; mt++)
#pragma unroll
      for (int r = 0; r < 4; r++)
        pmerge[wv][mt * 16 + 4 * g + r] = pool[mt][r];
  }
  __syncthreads();
  if (tid < 128) {
    float v = fmaxf(fmaxf(pmerge[0][tid], pmerge[1][tid]),
                    fmaxf(pmerge[2][tid], pmerge[3][tid]));
    ymax[(size_t)frame * 128 + tid] = v + eb3[tid];
  }
}

// ====== fused transformer: 1 block/batch, 512 threads (8 waves) ======
__global__ __launch_bounds__(512, 1) void xformer_kernel(
    const float* __restrict__ ymax, const int* __restrict__ fl,
    const float* __restrict__ ctok, const float* __restrict__ cpos,
    const unsigned short* __restrict__ wbf,
    const float* __restrict__ in_b, const float* __restrict__ ob,
    const float* __restrict__ l1g, const float* __restrict__ l1b,
    const float* __restrict__ f1b, const float* __restrict__ f2b,
    const float* __restrict__ l2g, const float* __restrict__ l2b,
    float* __restrict__ zbuf)
{
  __shared__ __align__(16) float ylds[64 * 128];           // 32 KB
  __shared__ __align__(16) unsigned short ubuf[64 * 256];  // 32 KB: O | vb, later ffs
  __shared__ __align__(16) unsigned short kq4[2][8][4][64][4]; // 32 KB: Q(scaled), K frag pieces
  const int b = blockIdx.x, tid = threadIdx.x;
  const int w8 = tid >> 6, lane = tid & 63, c = lane & 15, g = lane >> 4;
  const int h = w8 >> 1, sub = w8 & 1;
  const int flb = fl[b];
  const float scl = 0.17677669529663687f;

  // ---- assemble y ----
  for (int it = 0; it < 16; it++) {
    int idx = it * 512 + tid;
    int t = idx >> 7, d = idx & 127;
    float v;
    if (t == 0) v = ctok[d] + cpos[d];
    else if (t <= 60) {
      int f = t - 1;
      float ym = (f < flb) ? ymax[(size_t)(b * 60 + f) * 128 + d] : 0.f;
      float dv = __expf((float)(d & ~1) * (-0.07195578416f));
      float ang = (float)f * dv;
      v = ym + ((d & 1) ? __cosf(ang) : __sinf(ang));
    } else v = 0.f;
    ylds[YI(t, d)] = v;
  }
  __syncthreads();

  for (int l = 0; l < 2; l++) {
    const unsigned short* WL = wbf + 24576 + (size_t)l * 131072;
    const bf16x8* wq  = (const bf16x8*)WL;
    const bf16x8* wo  = (const bf16x8*)(WL + 49152);
    const bf16x8* w1p = (const bf16x8*)(WL + 65536);
    const bf16x8* w2p = (const bf16x8*)(WL + 98304);
    unsigned short* vb = ubuf + 8192 + h * 2048;

    // ---------- qkv: wave w8 computes channel tile 16*w8 of Q,K,V ----------
    {
      bf16x8 yB[4][4];
#pragma unroll
      for (int nt = 0; nt < 4; nt++)
#pragma unroll
        for (int ks = 0; ks < 4; ks++) {
          f32x4 lo = *(const f32x4*)&ylds[YI(16 * nt + c, 32 * ks + 4 * g)];
          f32x4 hi = *(const f32x4*)&ylds[YI(16 * nt + c, 32 * ks + 16 + 4 * g)];
          yB[nt][ks] = pack8(lo, hi);
        }
#pragma unroll
      for (int p = 0; p < 3; p++) {
        const int tq = p * 8 + w8;
        bf16x8 Af[4];
#pragma unroll
        for (int ks = 0; ks < 4; ks++) Af[ks] = wq[(tq * 4 + ks) * 64 + lane];
        f32x4 bias = *(const f32x4*)(in_b + l * 384 + p * 128 + 16 * w8 + 4 * g);
        f32x4 acc[4];
#pragma unroll
        for (int nt = 0; nt < 4; nt++) acc[nt] = bias;
#pragma unroll
        for (int ks = 0; ks < 4; ks++)
#pragma unroll
          for (int nt = 0; nt < 4; nt++)
            acc[nt] = __builtin_amdgcn_mfma_f32_16x16x32_bf16(Af[ks], yB[nt][ks], acc[nt], 0, 0, 0);
        if (p == 2) {
#pragma unroll
          for (int nt = 0; nt < 4; nt++)
            *(s16x4*)&vb[VI(16 * nt + c, 16 * sub + 4 * g)] = pack4(acc[nt]);
        } else {
#pragma unroll
          for (int nt = 0; nt < 4; nt++) {
            f32x4 sv = acc[nt];
            if (p == 0) sv = sv * scl;
            *(s16x4*)&kq4[p][w8][nt][lane][0] = pack4(sv);
          }
        }
      }
    }
    __syncthreads();

    // ---------- attention: wave (h, sub) handles q-tiles {2sub, 2sub+1} ----------
    {
      bf16x8 Ak[4], Bq2[2];
#pragma unroll
      for (int kt = 0; kt < 4; kt++) {
        s16x4 lo = *(const s16x4*)&kq4[1][2 * h][kt][lane][0];
        s16x4 hi = *(const s16x4*)&kq4[1][2 * h + 1][kt][lane][0];
        Ak[kt] = __builtin_shufflevector(lo, hi, 0, 1, 2, 3, 4, 5, 6, 7);
      }
#pragma unroll
      for (int j = 0; j < 2; j++) {
        s16x4 lo = *(const s16x4*)&kq4[0][2 * h][2 * sub + j][lane][0];
        s16x4 hi = *(const s16x4*)&kq4[0][2 * h + 1][2 * sub + j][lane][0];
        Bq2[j] = __builtin_shufflevector(lo, hi, 0, 1, 2, 3, 4, 5, 6, 7);
      }
      f32x4 St[4][2];
#pragma unroll
      for (int kt = 0; kt < 4; kt++)
#pragma unroll
        for (int j = 0; j < 2; j++) {
          f32x4 z = {0.f, 0.f, 0.f, 0.f};
          St[kt][j] = __builtin_amdgcn_mfma_f32_16x16x32_bf16(Ak[kt], Bq2[j], z, 0, 0, 0);
        }
#pragma unroll
      for (int j = 0; j < 2; j++) {
        float m = -1e30f;
#pragma unroll
        for (int kt = 0; kt < 4; kt++)
#pragma unroll
          for (int r = 0; r < 4; r++) {
            const int kp = 16 * kt + 4 * g + r;
            float s = St[kt][j][r];
            s = (kp > flb) ? -1e30f : s;
            St[kt][j][r] = s;
            m = fmaxf(m, s);
          }
        m = fmaxf(m, __shfl_xor(m, 16, 64));
        m = fmaxf(m, __shfl_xor(m, 32, 64));
        float sum = 0.f;
#pragma unroll
        for (int kt = 0; kt < 4; kt++)
#pragma unroll
          for (int r = 0; r < 4; r++) {
            float p = __expf(St[kt][j][r] - m);
            St[kt][j][r] = p;
            sum += p;
          }
        sum += __shfl_xor(sum, 16, 64);
        sum += __shfl_xor(sum, 32, 64);
        const float inv = 1.f / sum;
#pragma unroll
        for (int kt = 0; kt < 4; kt++)
#pragma unroll
          for (int r = 0; r < 4; r++) St[kt][j][r] *= inv;
      }
      bf16x8 Bp[2][2];
#pragma unroll
      for (int j = 0; j < 2; j++)
#pragma unroll
        for (int ks = 0; ks < 2; ks++) {
          bf16x8 r;
#pragma unroll
          for (int i = 0; i < 8; i++) r[i] = f2bf(St[2 * ks + (i >> 2)][j][i & 3]);
          Bp[j][ks] = r;
        }
      bf16x8 Av[2][2];
#pragma unroll
      for (int dt = 0; dt < 2; dt++)
#pragma unroll
        for (int ks = 0; ks < 2; ks++) {
          bf16x8 r;
#pragma unroll
          for (int i = 0; i < 8; i++) {
            const int kp = 32 * ks + 16 * (i >> 2) + 4 * g + (i & 3);
            r[i] = (short)vb[VI(kp, 16 * dt + c)];
          }
          Av[dt][ks] = r;
        }
#pragma unroll
      for (int dt = 0; dt < 2; dt++)
#pragma unroll
        for (int j = 0; j < 2; j++) {
          f32x4 z = {0.f, 0.f, 0.f, 0.f};
          z = __builtin_amdgcn_mfma_f32_16x16x32_bf16(Av[dt][0], Bp[j][0], z, 0, 0, 0);
          z = __builtin_amdgcn_mfma_f32_16x16x32_bf16(Av[dt][1], Bp[j][1], z, 0, 0, 0);
          *(s16x4*)&ubuf[OI(16 * (2 * sub + j) + c, 32 * h + 16 * dt + 4 * g)] = pack4(z);
        }
    }
    __syncthreads();

    // ---------- proj + residual: wave owns output tile j0 = 16*w8 ----------
    {
      bf16x8 Bo[4][4];
#pragma unroll
      for (int nt = 0; nt < 4; nt++)
#pragma unroll
        for (int ks = 0; ks < 4; ks++) {
          s16x4 lo = *(const s16x4*)&ubuf[OI(16 * nt + c, 32 * ks + 4 * g)];
          s16x4 hi = *(const s16x4*)&ubuf[OI(16 * nt + c, 32 * ks + 16 + 4 * g)];
          Bo[nt][ks] = __builtin_shufflevector(lo, hi, 0, 1, 2, 3, 4, 5, 6, 7);
        }
      const int j0 = 16 * w8;
      bf16x8 Af[4];
#pragma unroll
      for (int ks = 0; ks < 4; ks++) Af[ks] = wo[(w8 * 4 + ks) * 64 + lane];
      f32x4 bias = *(const f32x4*)(ob + l * 128 + j0 + 4 * g);
      f32x4 acc[4];
#pragma unroll
      for (int nt = 0; nt < 4; nt++) acc[nt] = bias;
#pragma unroll
      for (int ks = 0; ks < 4; ks++)
#pragma unroll
        for (int nt = 0; nt < 4; nt++)
          acc[nt] = __builtin_amdgcn_mfma_f32_16x16x32_bf16(Af[ks], Bo[nt][ks], acc[nt], 0, 0, 0);
#pragma unroll
      for (int nt = 0; nt < 4; nt++) {
        float* yp = &ylds[YI(16 * nt + c, j0 + 4 * g)];
        *(f32x4*)yp = *(const f32x4*)yp + acc[nt];
      }
    }
    __syncthreads();
    // ---------- LN1 ----------
    {
      const int t = 8 * w8 + (lane >> 3);
      const int s = lane & 7;
      f32x4 vv[4];
      float s1 = 0.f, s2 = 0.f;
#pragma unroll
      for (int k = 0; k < 4; k++) {
        vv[k] = *(const f32x4*)&ylds[YI(t, s * 16 + 4 * k)];
#pragma unroll
        for (int r = 0; r < 4; r++) { s1 += vv[k][r]; s2 = fmaf(vv[k][r], vv[k][r], s2); }
      }
      s1 += __shfl_xor(s1, 1, 64); s1 += __shfl_xor(s1, 2, 64); s1 += __shfl_xor(s1, 4, 64);
      s2 += __shfl_xor(s2, 1, 64); s2 += __shfl_xor(s2, 2, 64); s2 += __shfl_xor(s2, 4, 64);
      const float mean = s1 * 0.0078125f;
      const float var  = s2 * 0.0078125f - mean * mean;
      const float inv  = rsqrtf(var + EPSV);
#pragma unroll
      for (int k = 0; k < 4; k++) {
        f32x4 gg = *(const f32x4*)(l1g + l * 128 + s * 16 + 4 * k);
        f32x4 bb = *(const f32x4*)(l1b + l * 128 + s * 16 + 4 * k);
        f32x4 o;
#pragma unroll
        for (int r = 0; r < 4; r++) o[r] = (vv[k][r] - mean) * inv * gg[r] + bb[r];
        *(f32x4*)&ylds[YI(t, s * 16 + 4 * k)] = o;
      }
    }
    __syncthreads();

    // ---------- ff1 (relu): wave owns tiles w8 and w8+8 ----------
    {
      bf16x8 yB[4][4];
#pragma unroll
      for (int nt = 0; nt < 4; nt++)
#pragma unroll
        for (int ks = 0; ks < 4; ks++) {
          f32x4 lo = *(const f32x4*)&ylds[YI(16 * nt + c, 32 * ks + 4 * g)];
          f32x4 hi = *(const f32x4*)&ylds[YI(16 * nt + c, 32 * ks + 16 + 4 * g)];
          yB[nt][ks] = pack8(lo, hi);
        }
#pragma unroll
      for (int half = 0; half < 2; half++) {
        const int t16 = 8 * half + w8;
        bf16x8 Af[4];
#pragma unroll
        for (int ks = 0; ks < 4; ks++) Af[ks] = w1p[(t16 * 4 + ks) * 64 + lane];
        f32x4 bias = *(const f32x4*)(f1b + l * 256 + 16 * t16 + 4 * g);
        f32x4 acc[4];
#pragma unroll
        for (int nt = 0; nt < 4; nt++) acc[nt] = bias;
#pragma unroll
        for (int ks = 0; ks < 4; ks++)
#pragma unroll
          for (int nt = 0; nt < 4; nt++)
            acc[nt] = __builtin_amdgcn_mfma_f32_16x16x32_bf16(Af[ks], yB[nt][ks], acc[nt], 0, 0, 0);
#pragma unroll
        for (int nt = 0; nt < 4; nt++) {
          f32x4 rl;
#pragma unroll
          for (int r = 0; r < 4; r++) rl[r] = fmaxf(acc[nt][r], 0.f);
          *(s16x4*)&ubuf[FI(16 * nt + c, 16 * t16 + 4 * g)] = pack4(rl);
        }
      }
    }
    __syncthreads();
    // ---------- ff2 + residual: wave owns output tile 16*w8 ----------
    {
      f32x4 acc[4];
      f32x4 bias = *(const f32x4*)(f2b + l * 128 + 16 * w8 + 4 * g);
#pragma unroll
      for (int nt = 0; nt < 4; nt++) acc[nt] = bias;
#pragma unroll
      for (int ks = 0; ks < 8; ks++) {
        bf16x8 Af = w2p[(w8 * 8 + ks) * 64 + lane];
        bf16x8 Bf[4];
#pragma unroll
        for (int nt = 0; nt < 4; nt++) {
          s16x4 lo = *(const s16x4*)&ubuf[FI(16 * nt + c, 32 * ks + 4 * g)];
          s16x4 hi = *(const s16x4*)&ubuf[FI(16 * nt + c, 32 * ks + 16 + 4 * g)];
          Bf[nt] = __builtin_shufflevector(lo, hi, 0, 1, 2, 3, 4, 5, 6, 7);
        }
#pragma unroll
        for (int nt = 0; nt < 4; nt++)
          acc[nt] = __builtin_amdgcn_mfma_f32_16x16x32_bf16(Af, Bf[nt], acc[nt], 0, 0, 0);
      }
#pragma unroll
      for (int nt = 0; nt < 4; nt++) {
        float* yp = &ylds[YI(16 * nt + c, 16 * w8 + 4 * g)];
        *(f32x4*)yp = *(const f32x4*)yp + acc[nt];
      }
    }
    __syncthreads();
    // ---------- LN2 ----------
    {
      const int t = 8 * w8 + (lane >> 3);
      const int s = lane & 7;
      f32x4 vv[4];
      float s1 = 0.f, s2 = 0.f;
#pragma unroll
      for (int k = 0; k < 4; k++) {
        vv[k] = *(const f32x4*)&ylds[YI(t, s * 16 + 4 * k)];
#pragma unroll
        for (int r = 0; r < 4; r++) { s1 += vv[k][r]; s2 = fmaf(vv[k][r], vv[k][r], s2); }
      }
      s1 += __shfl_xor(s1, 1, 64); s1 += __shfl_xor(s1, 2, 64); s1 += __shfl_xor(s1, 4, 64);
      s2 += __shfl_xor(s2, 1, 64); s2 += __shfl_xor(s2, 2, 64); s2 += __shfl_xor(s2, 4, 64);
      const float mean = s1 * 0.0078125f;
      const float var  = s2 * 0.0078125f - mean * mean;
      const float inv  = rsqrtf(var + EPSV);
#pragma unroll
      for (int k = 0; k < 4; k++) {
        f32x4 gg = *(const f32x4*)(l2g + l * 128 + s * 16 + 4 * k);
        f32x4 bb = *(const f32x4*)(l2b + l * 128 + s * 16 + 4 * k);
        f32x4 o;
#pragma unroll
        for (int r = 0; r < 4; r++) o[r] = (vv[k][r] - mean) * inv * gg[r] + bb[r];
        *(f32x4*)&ylds[YI(t, s * 16 + 4 * k)] = o;
      }
    }
    __syncthreads();
  }

  if (tid < 128) zbuf[b * 256 + tid] = ylds[YI(0, tid)];
  else if (tid < 256) zbuf[b * 256 + tid] = ylds[YI(flb, tid - 128)];
}

// ---------------- classifier head with live batch-norm (single block) ----------------
__global__ __launch_bounds__(256) void head_kernel(
    const float* __restrict__ zbuf,
    const float* __restrict__ fc1w, const float* __restrict__ fc1b,
    const float* __restrict__ bn1g, const float* __restrict__ bn1b,
    const float* __restrict__ fc15w, const float* __restrict__ fc15b,
    const float* __restrict__ bn15g, const float* __restrict__ bn15b,
    const float* __restrict__ fc2w, const float* __restrict__ fc2b,
    const float* __restrict__ bn2g, const float* __restrict__ bn2b,
    const float* __restrict__ fcw, const float* __restrict__ fcb,
    float* __restrict__ out)
{
  __shared__ float zc[16 * 256];
  __shared__ float t1[16 * 128];
  __shared__ float t15[16 * 64];
  __shared__ float t2[16 * 32];
  const int tid = threadIdx.x;

  for (int idx = tid; idx < 16 * 256; idx += 256) zc[idx] = zbuf[idx];
  __syncthreads();

  for (int idx = tid; idx < 16 * 128; idx += 256) {
    const int b = idx >> 7, j = idx & 127;
    float a = fc1b[j];
    for (int k = 0; k < 256; k++) a = fmaf(zc[b * 256 + k], fc1w[k * 128 + j], a);
    t1[idx] = a;
  }
  __syncthreads();
  if (tid < 128) {
    const int j = tid;
    float s1 = 0.f, s2 = 0.f;
    for (int b = 0; b < 16; b++) { const float v = t1[b * 128 + j]; s1 += v; s2 = fmaf(v, v, s2); }
    const float m = s1 * (1.f / 16.f);
    const float var = s2 * (1.f / 16.f) - m * m;
    const float scl = bn1g[j] / sqrtf(var + EPSV);
    const float sh = bn1b[j] - m * scl;
    for (int b = 0; b < 16; b++) {
      const float v = t1[b * 128 + j] * scl + sh;
      t1[b * 128 + j] = (v > 0.f) ? v : 0.2f * v;
    }
  }
  __syncthreads();

  for (int idx = tid; idx < 16 * 64; idx += 256) {
    const int b = idx >> 6, j = idx & 63;
    float a = fc15b[j];
    for (int k = 0; k < 128; k++) a = fmaf(t1[b * 128 + k], fc15w[k * 64 + j], a);
    t15[idx] = a;
  }
  __syncthreads();
  if (tid < 64) {
    const int j = tid;
    float s1 = 0.f, s2 = 0.f;
    for (int b = 0; b < 16; b++) { const float v = t15[b * 64 + j]; s1 += v; s2 = fmaf(v, v, s2); }
    const float m = s1 * (1.f / 16.f);
    const float var = s2 * (1.f / 16.f) - m * m;
    const float scl = bn15g[j] / sqrtf(var + EPSV);
    const float sh = bn15b[j] - m * scl;
    for (int b = 0; b < 16; b++) {
      const float v = t15[b * 64 + j] * scl + sh;
      t15[b * 64 + j] = (v > 0.f) ? v : 0.2f * v;
    }
  }
  __syncthreads();

  for (int idx = tid; idx < 16 * 32; idx += 256) {
    const int b = idx >> 5, j = idx & 31;
    float a = fc2b[j];
    for (int k = 0; k < 64; k++) a = fmaf(t15[b * 64 + k], fc2w[k * 32 + j], a);
    t2[idx] = a;
  }
  __syncthreads();
  if (tid < 32) {
    const int j = tid;
    float s1 = 0.f, s2 = 0.f;
    for (int b = 0; b < 16; b++) { const float v = t2[b * 32 + j]; s1 += v; s2 = fmaf(v, v, s2); }
    const float m = s1 * (1.f / 16.f);
    const float var = s2 * (1.f / 16.f) - m * m;
    const float scl = bn2g[j] / sqrtf(var + EPSV);
    const float sh = bn2b[j] - m * scl;
    for (int b = 0; b < 16; b++) {
      const float v = t2[b * 32 + j] * scl + sh;
      t2[b * 32 + j] = (v > 0.f) ? v : 0.2f * v;
    }
  }
  __syncthreads();

  for (int idx = tid; idx < 16 * 27; idx += 256) {
    const int b = idx / 27, cc = idx % 27;
    float a = fcb[cc];
    for (int k = 0; k < 32; k++) a = fmaf(t2[b * 32 + k], fcw[k * 27 + cc], a);
    out[b * 27 + cc] = a;
  }
}

extern "C" void kernel_launch(void* const* d_in, const int* in_sizes, int n_in,
                              void* d_out, int out_size, void* d_ws, size_t ws_size,
                              hipStream_t stream)
{
  const float* x    = (const float*)d_in[0];
  const int*   fl   = (const int*)d_in[1];
  const float* ew1  = (const float*)d_in[2];  const float* eb1 = (const float*)d_in[3];
  const float* ew2  = (const float*)d_in[4];  const float* eb2 = (const float*)d_in[5];
  const float* ew3  = (const float*)d_in[6];  const float* eb3 = (const float*)d_in[7];
  const float* ctok = (const float*)d_in[8];  const float* cpos = (const float*)d_in[9];
  const float* in_w = (const float*)d_in[10]; const float* in_b = (const float*)d_in[11];
  const float* ow   = (const float*)d_in[12]; const float* ob   = (const float*)d_in[13];
  const float* l1g  = (const float*)d_in[14]; const float* l1b  = (const float*)d_in[15];
  const float* f1w  = (const float*)d_in[16]; const float* f1b  = (const float*)d_in[17];
  const float* f2w  = (const float*)d_in[18]; const float* f2b  = (const float*)d_in[19];
  const float* l2g  = (const float*)d_in[20]; const float* l2b  = (const float*)d_in[21];
  const float* fc1w = (const float*)d_in[22]; const float* fc1b = (const float*)d_in[23];
  const float* bn1g = (const float*)d_in[24]; const float* bn1b = (const float*)d_in[25];
  const float* fc15w= (const float*)d_in[26]; const float* fc15b= (const float*)d_in[27];
  const float* bn15g= (const float*)d_in[28]; const float* bn15b= (const float*)d_in[29];
  const float* fc2w = (const float*)d_in[30]; const float* fc2b = (const float*)d_in[31];
  const float* bn2g = (const float*)d_in[32]; const float* bn2b = (const float*)d_in[33];
  const float* fcw  = (const float*)d_in[34]; const float* fcb  = (const float*)d_in[35];
  float* out = (float*)d_out;

  char* w = (char*)d_ws;
  float* ymax = (float*)w;                                   // 491520 B
  float* zbuf = (float*)(w + 491520);                        // 16384 B
  unsigned short* wbf = (unsigned short*)(w + 507904);       // 573440 B (286720 shorts)

  prep_kernel<<<1120, 256, 0, stream>>>(ew2, ew3, in_w, ow, f1w, f2w, wbf);
  enc_kernel<<<960, 256, 0, stream>>>(x, ew1, eb1, eb2, eb3, wbf, ymax);
  xformer_kernel<<<16, 512, 0, stream>>>(ymax, fl, ctok, cpos, wbf, in_b, ob,
                                         l1g, l1b, f1b, f2b, l2g, l2b, zbuf);
  head_kernel<<<1, 256, 0, stream>>>(zbuf, fc1w, fc1b, bn1g, bn1b,
                                     fc15w, fc15b, bn15g, bn15b,
                                     fc2w, fc2b, bn2g, bn2b, fcw, fcb, out);
}

// Round 5
// 107.388 us; speedup vs baseline: 6.8901x; 1.1039x over previous
//
#include <hip/hip_runtime.h>
#include <math.h>

#define SS 61
#define EPSV 1e-5f

typedef __attribute__((ext_vector_type(8))) short bf16x8;
typedef __attribute__((ext_vector_type(4))) short s16x4;
typedef __attribute__((ext_vector_type(4))) float f32x4;

__device__ __forceinline__ short f2bf(float f){
  return __builtin_bit_cast(short, (__bf16)f);
}
__device__ __forceinline__ float bf2f(short s){
  unsigned u = ((unsigned)(unsigned short)s) << 16;
  return __builtin_bit_cast(float, u);
}
__device__ __forceinline__ bf16x8 pack8(f32x4 lo, f32x4 hi){
  bf16x8 r;
  r[0]=f2bf(lo[0]); r[1]=f2bf(lo[1]); r[2]=f2bf(lo[2]); r[3]=f2bf(lo[3]);
  r[4]=f2bf(hi[0]); r[5]=f2bf(hi[1]); r[6]=f2bf(hi[2]); r[7]=f2bf(hi[3]);
  return r;
}
__device__ __forceinline__ s16x4 pack4(f32x4 v){
  s16x4 r; r[0]=f2bf(v[0]); r[1]=f2bf(v[1]); r[2]=f2bf(v[2]); r[3]=f2bf(v[3]); return r;
}
// xformer swizzles (unchanged, verified R3/R4)
#define YI(t,d) (((t)<<7) + ((d) ^ (((t)&7)<<2)))
#define OI(t,e) (((t)<<7) + ((e) ^ (((t)&7)<<2)))
#define FI(t,e) (((t)<<8) + ((e) ^ (((t)&7)<<2)))
#define VI(k,d) (((k)<<5) + ((d) ^ (((k)&7)<<2)))
// enc LDS (byte offsets, slot-ordered rows, XOR-swizzled 16B granules)
#define H1A(pt,idx) ((pt)*128 + (((idx)*2) ^ (((pt)&7)<<4)))
#define H2A(pt,idx) ((pt)*256 + (((idx)*2) ^ (((pt)&15)<<4)))

// ================= weight prep: fp32 -> bf16 fragment-linear =================
// frags: 0..3 A1hi, 4..7 A1lo, 8..23 A2 (mt*2+ks), 24..55 A3 (mt*4+ks),
//        56 + l*256: qkv 96 | ow 32 | f1 64 | f2 64.  All sigma k-map.
__global__ __launch_bounds__(256) void prep_kernel(
    const float* __restrict__ ew1, const float* __restrict__ eb1,
    const float* __restrict__ ew2, const float* __restrict__ ew3,
    const float* __restrict__ in_w, const float* __restrict__ ow,
    const float* __restrict__ f1w, const float* __restrict__ f2w,
    unsigned short* __restrict__ wbf)
{
  int s = blockIdx.x * 256 + threadIdx.x;   // 0..290815
  int i = s & 7, lane = (s >> 3) & 63, frag = s >> 9;
  int c = lane & 15, g = lane >> 4;
  int sig = 16 * (i >> 2) + 4 * g + (i & 3);
  unsigned short outv;
  if (frag < 8) {
    int mt = frag & 3;
    float base = (sig < 3) ? ew1[sig * 64 + 16 * mt + c]
               : (sig == 3 ? eb1[16 * mt + c] : 0.f);
    short hv = f2bf(base);
    if (frag < 4) outv = (unsigned short)hv;
    else { float rv = base - bf2f(hv); outv = (unsigned short)f2bf(rv); }
  } else if (frag < 24) {
    int f = frag - 8; int mt = f >> 1, ks = f & 1;
    outv = (unsigned short)f2bf(ew2[(32 * ks + sig) * 128 + 16 * mt + c]);
  } else if (frag < 56) {
    int f = frag - 24; int mt = f >> 2, ks = f & 3;
    outv = (unsigned short)f2bf(ew3[(32 * ks + sig) * 128 + 16 * mt + c]);
  } else {
    int f = frag - 56; int l = f >> 8; f &= 255;
    float v;
    if (f < 96) { int tq = f >> 2, ks = f & 3;
      v = in_w[(size_t)l * 49152 + (size_t)(16 * tq + c) * 128 + 32 * ks + sig]; }
    else if (f < 128) { int f3 = f - 96; int t = f3 >> 2, ks = f3 & 3;
      v = ow[(size_t)l * 16384 + (size_t)(16 * t + c) * 128 + 32 * ks + sig]; }
    else if (f < 192) { int f3 = f - 128; int t = f3 >> 2, ks = f3 & 3;
      v = f1w[(size_t)l * 32768 + (size_t)(16 * t + c) * 128 + 32 * ks + sig]; }
    else { int f3 = f - 192; int t = f3 >> 3, ks = f3 & 7;
      v = f2w[(size_t)l * 32768 + (size_t)(16 * t + c) * 256 + 32 * ks + sig]; }
    outv = (unsigned short)f2bf(v);
  }
  wbf[s] = outv;
}

// ====== encoder: cooperative 4-wave block, 1 frame/block, 64 pts/iter ======
// wave (mh,gh): L1 for grp=wv; L2/L3 for mtiles {4mh..4mh+3}, grps {2gh,2gh+1}.
__global__ __launch_bounds__(256) void enc_kernel(
    const float* __restrict__ x,
    const float* __restrict__ eb2, const float* __restrict__ eb3,
    const unsigned short* __restrict__ wbf,
    float* __restrict__ ymax)
{
  __shared__ __align__(16) unsigned short h1p[64 * 64];    // 8 KB
  __shared__ __align__(16) unsigned short h2p[64 * 128];   // 16 KB
  __shared__ float pmerge[2][128];
  const int tid = threadIdx.x, lane = tid & 63, wv = tid >> 6;
  const int c = lane & 15, g = lane >> 4;
  const int mh = wv & 1, gh = wv >> 1;
  const int frame = blockIdx.x;
  const bf16x8* wf = (const bf16x8*)wbf;

  bf16x8 A1h[4], A1l[4];
#pragma unroll
  for (int mt = 0; mt < 4; mt++) { A1h[mt] = wf[mt * 64 + lane]; A1l[mt] = wf[(4 + mt) * 64 + lane]; }
  bf16x8 A2f[4][2];
#pragma unroll
  for (int j = 0; j < 4; j++)
#pragma unroll
    for (int ks = 0; ks < 2; ks++) A2f[j][ks] = wf[(8 + (4 * mh + j) * 2 + ks) * 64 + lane];
  bf16x8 A3f[4][4];
#pragma unroll
  for (int j = 0; j < 4; j++)
#pragma unroll
    for (int ks = 0; ks < 4; ks++) A3f[j][ks] = wf[(24 + (4 * mh + j) * 4 + ks) * 64 + lane];
  f32x4 b2v[4];
#pragma unroll
  for (int j = 0; j < 4; j++) b2v[j] = *(const f32x4*)(eb2 + 16 * (4 * mh + j) + 4 * g);

  f32x4 pool[4];
#pragma unroll
  for (int j = 0; j < 4; j++) pool[j] = {-1e30f, -1e30f, -1e30f, -1e30f};

  const float* xf = x + (size_t)frame * 1536;
  float nx0, nx1, nx2;
  { const float* xp = xf + (16 * wv + c) * 3; nx0 = xp[0]; nx1 = xp[1]; nx2 = xp[2]; }

  const int ptw = 16 * wv + c;   // this wave's L1 point (within 64-group)

  for (int t = 0; t < 8; t++) {
    const float x0 = nx0, x1 = nx1, x2 = nx2;
    if (t < 7) {
      const float* xp = xf + ((t + 1) * 64 + 16 * wv + c) * 3;
      nx0 = xp[0]; nx1 = xp[1]; nx2 = xp[2];
    }
    // ---- L1: hi/lo bf16 split (~fp32 exact), MFMA ----
    bf16x8 bxh = {0,0,0,0,0,0,0,0}, bxl = {0,0,0,0,0,0,0,0};
    if (g == 0) {
      short h0 = f2bf(x0), h1_ = f2bf(x1), h2_ = f2bf(x2);
      bxh[0] = h0; bxh[1] = h1_; bxh[2] = h2_; bxh[3] = (short)0x3F80;
      bxl[0] = f2bf(x0 - bf2f(h0)); bxl[1] = f2bf(x1 - bf2f(h1_)); bxl[2] = f2bf(x2 - bf2f(h2_));
    }
#pragma unroll
    for (int mt = 0; mt < 4; mt++) {
      f32x4 a = {0.f, 0.f, 0.f, 0.f};
      a = __builtin_amdgcn_mfma_f32_16x16x32_bf16(A1h[mt], bxh, a, 0, 0, 0);
      a = __builtin_amdgcn_mfma_f32_16x16x32_bf16(A1h[mt], bxl, a, 0, 0, 0);
      a = __builtin_amdgcn_mfma_f32_16x16x32_bf16(A1l[mt], bxh, a, 0, 0, 0);
      f32x4 rl;
#pragma unroll
      for (int r = 0; r < 4; r++) rl[r] = fmaxf(a[r], 0.f);
      *(s16x4*)((char*)h1p + H1A(ptw, (mt >> 1) * 32 + g * 8 + (mt & 1) * 4)) = pack4(rl);
    }
    __syncthreads();
    // ---- L2: mtiles 4mh..+3 for grps 2gh,2gh+1 ----
    bf16x8 B2[2][2];
#pragma unroll
    for (int gi = 0; gi < 2; gi++)
#pragma unroll
      for (int ks = 0; ks < 2; ks++) {
        const int pt = 16 * (2 * gh + gi) + c;
        B2[gi][ks] = *(const bf16x8*)((const char*)h1p + H1A(pt, ks * 32 + g * 8));
      }
#pragma unroll
    for (int j = 0; j < 4; j++)
#pragma unroll
      for (int gi = 0; gi < 2; gi++) {
        f32x4 a = b2v[j];
        a = __builtin_amdgcn_mfma_f32_16x16x32_bf16(A2f[j][0], B2[gi][0], a, 0, 0, 0);
        a = __builtin_amdgcn_mfma_f32_16x16x32_bf16(A2f[j][1], B2[gi][1], a, 0, 0, 0);
        f32x4 rl;
#pragma unroll
        for (int r = 0; r < 4; r++) rl[r] = fmaxf(a[r], 0.f);
        const int mt = 4 * mh + j;
        const int pt = 16 * (2 * gh + gi) + c;
        *(s16x4*)((char*)h2p + H2A(pt, (mt >> 1) * 32 + g * 8 + (mt & 1) * 4)) = pack4(rl);
      }
    __syncthreads();
    // ---- L3: mtiles 4mh..+3 for grps 2gh,2gh+1; running max-pool ----
    bf16x8 B3[2][4];
#pragma unroll
    for (int gi = 0; gi < 2; gi++)
#pragma unroll
      for (int ks = 0; ks < 4; ks++) {
        const int pt = 16 * (2 * gh + gi) + c;
        B3[gi][ks] = *(const bf16x8*)((const char*)h2p + H2A(pt, ks * 32 + g * 8));
      }
#pragma unroll
    for (int j = 0; j < 4; j++)
#pragma unroll
      for (int gi = 0; gi < 2; gi++) {
        f32x4 a = {0.f, 0.f, 0.f, 0.f};
        a = __builtin_amdgcn_mfma_f32_16x16x32_bf16(A3f[j][0], B3[gi][0], a, 0, 0, 0);
        a = __builtin_amdgcn_mfma_f32_16x16x32_bf16(A3f[j][1], B3[gi][1], a, 0, 0, 0);
        a = __builtin_amdgcn_mfma_f32_16x16x32_bf16(A3f[j][2], B3[gi][2], a, 0, 0, 0);
        a = __builtin_amdgcn_mfma_f32_16x16x32_bf16(A3f[j][3], B3[gi][3], a, 0, 0, 0);
#pragma unroll
        for (int r = 0; r < 4; r++) pool[j][r] = fmaxf(pool[j][r], a[r]);
      }
  }

  // reduce over 16 point-columns; merge gh halves via LDS
#pragma unroll
  for (int j = 0; j < 4; j++)
#pragma unroll
    for (int r = 0; r < 4; r++) {
      float v = pool[j][r];
      v = fmaxf(v, __shfl_xor(v, 1, 64));
      v = fmaxf(v, __shfl_xor(v, 2, 64));
      v = fmaxf(v, __shfl_xor(v, 4, 64));
      v = fmaxf(v, __shfl_xor(v, 8, 64));
      pool[j][r] = v;
    }
  if (c == 0) {
#pragma unroll
    for (int j = 0; j < 4; j++)
      *(f32x4*)&pmerge[gh][64 * mh + 16 * j + 4 * g] = pool[j];
  }
  __syncthreads();
  if (tid < 128)
    ymax[(size_t)frame * 128 + tid] = fmaxf(pmerge[0][tid], pmerge[1][tid]) + eb3[tid];
}

// ====== fused transformer: 1 block/batch, 512 threads, phase-ahead W prefetch ======
__global__ __launch_bounds__(512, 1) void xformer_kernel(
    const float* __restrict__ ymax, const int* __restrict__ fl,
    const float* __restrict__ ctok, const float* __restrict__ cpos,
    const unsigned short* __restrict__ wbf,
    const float* __restrict__ in_b, const float* __restrict__ ob,
    const float* __restrict__ l1g, const float* __restrict__ l1b,
    const float* __restrict__ f1b, const float* __restrict__ f2b,
    const float* __restrict__ l2g, const float* __restrict__ l2b,
    float* __restrict__ zbuf)
{
  __shared__ __align__(16) float ylds[64 * 128];
  __shared__ __align__(16) unsigned short ubuf[64 * 256];
  __shared__ __align__(16) unsigned short kq4[2][8][4][64][4];
  const int b = blockIdx.x, tid = threadIdx.x;
  const int w8 = tid >> 6, lane = tid & 63, c = lane & 15, g = lane >> 4;
  const int h = w8 >> 1, sub = w8 & 1;
  const int flb = fl[b];
  const float scl = 0.17677669529663687f;

  for (int it = 0; it < 16; it++) {
    int idx = it * 512 + tid;
    int t = idx >> 7, d = idx & 127;
    float v;
    if (t == 0) v = ctok[d] + cpos[d];
    else if (t <= 60) {
      int f = t - 1;
      float ym = (f < flb) ? ymax[(size_t)(b * 60 + f) * 128 + d] : 0.f;
      float dv = __expf((float)(d & ~1) * (-0.07195578416f));
      float ang = (float)f * dv;
      v = ym + ((d & 1) ? __cosf(ang) : __sinf(ang));
    } else v = 0.f;
    ylds[YI(t, d)] = v;
  }

  // prefetch qkv weights for layer 0
  bf16x8 wqf[12];
  {
    const bf16x8* wq0 = (const bf16x8*)(wbf + 28672);
#pragma unroll
    for (int p = 0; p < 3; p++)
#pragma unroll
      for (int ks = 0; ks < 4; ks++)
        wqf[p * 4 + ks] = wq0[((p * 8 + w8) * 4 + ks) * 64 + lane];
  }
  __syncthreads();

  for (int l = 0; l < 2; l++) {
    const unsigned short* WL = wbf + 28672 + (size_t)l * 131072;
    const bf16x8* wo  = (const bf16x8*)(WL + 49152);
    const bf16x8* w1p = (const bf16x8*)(WL + 65536);
    const bf16x8* w2p = (const bf16x8*)(WL + 98304);
    unsigned short* vb = ubuf + 8192 + h * 2048;
    bf16x8 wof[4], w1f[8], w2f[8];

    // ---------- qkv (uses prefetched wqf; prefetch wo) ----------
    {
      bf16x8 yB[4][4];
#pragma unroll
      for (int nt = 0; nt < 4; nt++)
#pragma unroll
        for (int ks = 0; ks < 4; ks++) {
          f32x4 lo = *(const f32x4*)&ylds[YI(16 * nt + c, 32 * ks + 4 * g)];
          f32x4 hi = *(const f32x4*)&ylds[YI(16 * nt + c, 32 * ks + 16 + 4 * g)];
          yB[nt][ks] = pack8(lo, hi);
        }
#pragma unroll
      for (int ks = 0; ks < 4; ks++) wof[ks] = wo[(w8 * 4 + ks) * 64 + lane];
#pragma unroll
      for (int p = 0; p < 3; p++) {
        f32x4 bias = *(const f32x4*)(in_b + l * 384 + p * 128 + 16 * w8 + 4 * g);
        f32x4 acc[4];
#pragma unroll
        for (int nt = 0; nt < 4; nt++) acc[nt] = bias;
#pragma unroll
        for (int ks = 0; ks < 4; ks++)
#pragma unroll
          for (int nt = 0; nt < 4; nt++)
            acc[nt] = __builtin_amdgcn_mfma_f32_16x16x32_bf16(wqf[p * 4 + ks], yB[nt][ks], acc[nt], 0, 0, 0);
        if (p == 2) {
#pragma unroll
          for (int nt = 0; nt < 4; nt++)
            *(s16x4*)&vb[VI(16 * nt + c, 16 * sub + 4 * g)] = pack4(acc[nt]);
        } else {
#pragma unroll
          for (int nt = 0; nt < 4; nt++) {
            f32x4 sv = acc[nt];
            if (p == 0) sv = sv * scl;
            *(s16x4*)&kq4[p][w8][nt][lane][0] = pack4(sv);
          }
        }
      }
    }
    __syncthreads();

    // ---------- attention ----------
    {
      bf16x8 Ak[4], Bq2[2];
#pragma unroll
      for (int kt = 0; kt < 4; kt++) {
        s16x4 lo = *(const s16x4*)&kq4[1][2 * h][kt][lane][0];
        s16x4 hi = *(const s16x4*)&kq4[1][2 * h + 1][kt][lane][0];
        Ak[kt] = __builtin_shufflevector(lo, hi, 0, 1, 2, 3, 4, 5, 6, 7);
      }
#pragma unroll
      for (int j = 0; j < 2; j++) {
        s16x4 lo = *(const s16x4*)&kq4[0][2 * h][2 * sub + j][lane][0];
        s16x4 hi = *(const s16x4*)&kq4[0][2 * h + 1][2 * sub + j][lane][0];
        Bq2[j] = __builtin_shufflevector(lo, hi, 0, 1, 2, 3, 4, 5, 6, 7);
      }
      f32x4 St[4][2];
#pragma unroll
      for (int kt = 0; kt < 4; kt++)
#pragma unroll
        for (int j = 0; j < 2; j++) {
          f32x4 z = {0.f, 0.f, 0.f, 0.f};
          St[kt][j] = __builtin_amdgcn_mfma_f32_16x16x32_bf16(Ak[kt], Bq2[j], z, 0, 0, 0);
        }
#pragma unroll
      for (int j = 0; j < 2; j++) {
        float m = -1e30f;
#pragma unroll
        for (int kt = 0; kt < 4; kt++)
#pragma unroll
          for (int r = 0; r < 4; r++) {
            const int kp = 16 * kt + 4 * g + r;
            float s = St[kt][j][r];
            s = (kp > flb) ? -1e30f : s;
            St[kt][j][r] = s;
            m = fmaxf(m, s);
          }
        m = fmaxf(m, __shfl_xor(m, 16, 64));
        m = fmaxf(m, __shfl_xor(m, 32, 64));
        float sum = 0.f;
#pragma unroll
        for (int kt = 0; kt < 4; kt++)
#pragma unroll
          for (int r = 0; r < 4; r++) {
            float p = __expf(St[kt][j][r] - m);
            St[kt][j][r] = p;
            sum += p;
          }
        sum += __shfl_xor(sum, 16, 64);
        sum += __shfl_xor(sum, 32, 64);
        const float inv = 1.f / sum;
#pragma unroll
        for (int kt = 0; kt < 4; kt++)
#pragma unroll
          for (int r = 0; r < 4; r++) St[kt][j][r] *= inv;
      }
      bf16x8 Bp[2][2];
#pragma unroll
      for (int j = 0; j < 2; j++)
#pragma unroll
        for (int ks = 0; ks < 2; ks++) {
          bf16x8 r;
#pragma unroll
          for (int i = 0; i < 8; i++) r[i] = f2bf(St[2 * ks + (i >> 2)][j][i & 3]);
          Bp[j][ks] = r;
        }
      bf16x8 Av[2][2];
#pragma unroll
      for (int dt = 0; dt < 2; dt++)
#pragma unroll
        for (int ks = 0; ks < 2; ks++) {
          bf16x8 r;
#pragma unroll
          for (int i = 0; i < 8; i++) {
            const int kp = 32 * ks + 16 * (i >> 2) + 4 * g + (i & 3);
            r[i] = (short)vb[VI(kp, 16 * dt + c)];
          }
          Av[dt][ks] = r;
        }
#pragma unroll
      for (int dt = 0; dt < 2; dt++)
#pragma unroll
        for (int j = 0; j < 2; j++) {
          f32x4 z = {0.f, 0.f, 0.f, 0.f};
          z = __builtin_amdgcn_mfma_f32_16x16x32_bf16(Av[dt][0], Bp[j][0], z, 0, 0, 0);
          z = __builtin_amdgcn_mfma_f32_16x16x32_bf16(Av[dt][1], Bp[j][1], z, 0, 0, 0);
          *(s16x4*)&ubuf[OI(16 * (2 * sub + j) + c, 32 * h + 16 * dt + 4 * g)] = pack4(z);
        }
    }
    __syncthreads();

    // ---------- proj + residual (uses wof; prefetch w1f) ----------
    {
      bf16x8 Bo[4][4];
#pragma unroll
      for (int nt = 0; nt < 4; nt++)
#pragma unroll
        for (int ks = 0; ks < 4; ks++) {
          s16x4 lo = *(const s16x4*)&ubuf[OI(16 * nt + c, 32 * ks + 4 * g)];
          s16x4 hi = *(const s16x4*)&ubuf[OI(16 * nt + c, 32 * ks + 16 + 4 * g)];
          Bo[nt][ks] = __builtin_shufflevector(lo, hi, 0, 1, 2, 3, 4, 5, 6, 7);
        }
#pragma unroll
      for (int half = 0; half < 2; half++)
#pragma unroll
        for (int ks = 0; ks < 4; ks++)
          w1f[half * 4 + ks] = w1p[((8 * half + w8) * 4 + ks) * 64 + lane];
      const int j0 = 16 * w8;
      f32x4 bias = *(const f32x4*)(ob + l * 128 + j0 + 4 * g);
      f32x4 acc[4];
#pragma unroll
      for (int nt = 0; nt < 4; nt++) acc[nt] = bias;
#pragma unroll
      for (int ks = 0; ks < 4; ks++)
#pragma unroll
        for (int nt = 0; nt < 4; nt++)
          acc[nt] = __builtin_amdgcn_mfma_f32_16x16x32_bf16(wof[ks], Bo[nt][ks], acc[nt], 0, 0, 0);
#pragma unroll
      for (int nt = 0; nt < 4; nt++) {
        float* yp = &ylds[YI(16 * nt + c, j0 + 4 * g)];
        *(f32x4*)yp = *(const f32x4*)yp + acc[nt];
      }
    }
    __syncthreads();
    // ---------- LN1 ----------
    {
      const int t = 8 * w8 + (lane >> 3);
      const int s = lane & 7;
      f32x4 vv[4];
      float s1 = 0.f, s2 = 0.f;
#pragma unroll
      for (int k = 0; k < 4; k++) {
        vv[k] = *(const f32x4*)&ylds[YI(t, s * 16 + 4 * k)];
#pragma unroll
        for (int r = 0; r < 4; r++) { s1 += vv[k][r]; s2 = fmaf(vv[k][r], vv[k][r], s2); }
      }
      s1 += __shfl_xor(s1, 1, 64); s1 += __shfl_xor(s1, 2, 64); s1 += __shfl_xor(s1, 4, 64);
      s2 += __shfl_xor(s2, 1, 64); s2 += __shfl_xor(s2, 2, 64); s2 += __shfl_xor(s2, 4, 64);
      const float mean = s1 * 0.0078125f;
      const float var  = s2 * 0.0078125f - mean * mean;
      const float inv  = rsqrtf(var + EPSV);
#pragma unroll
      for (int k = 0; k < 4; k++) {
        f32x4 gg = *(const f32x4*)(l1g + l * 128 + s * 16 + 4 * k);
        f32x4 bb = *(const f32x4*)(l1b + l * 128 + s * 16 + 4 * k);
        f32x4 o;
#pragma unroll
        for (int r = 0; r < 4; r++) o[r] = (vv[k][r] - mean) * inv * gg[r] + bb[r];
        *(f32x4*)&ylds[YI(t, s * 16 + 4 * k)] = o;
      }
    }
    __syncthreads();

    // ---------- ff1 (uses w1f; prefetch w2f) ----------
    {
      bf16x8 yB[4][4];
#pragma unroll
      for (int nt = 0; nt < 4; nt++)
#pragma unroll
        for (int ks = 0; ks < 4; ks++) {
          f32x4 lo = *(const f32x4*)&ylds[YI(16 * nt + c, 32 * ks + 4 * g)];
          f32x4 hi = *(const f32x4*)&ylds[YI(16 * nt + c, 32 * ks + 16 + 4 * g)];
          yB[nt][ks] = pack8(lo, hi);
        }
#pragma unroll
      for (int ks = 0; ks < 8; ks++) w2f[ks] = w2p[(w8 * 8 + ks) * 64 + lane];
#pragma unroll
      for (int half = 0; half < 2; half++) {
        const int t16 = 8 * half + w8;
        f32x4 bias = *(const f32x4*)(f1b + l * 256 + 16 * t16 + 4 * g);
        f32x4 acc[4];
#pragma unroll
        for (int nt = 0; nt < 4; nt++) acc[nt] = bias;
#pragma unroll
        for (int ks = 0; ks < 4; ks++)
#pragma unroll
          for (int nt = 0; nt < 4; nt++)
            acc[nt] = __builtin_amdgcn_mfma_f32_16x16x32_bf16(w1f[half * 4 + ks], yB[nt][ks], acc[nt], 0, 0, 0);
#pragma unroll
        for (int nt = 0; nt < 4; nt++) {
          f32x4 rl;
#pragma unroll
          for (int r = 0; r < 4; r++) rl[r] = fmaxf(acc[nt][r], 0.f);
          *(s16x4*)&ubuf[FI(16 * nt + c, 16 * t16 + 4 * g)] = pack4(rl);
        }
      }
    }
    __syncthreads();
    // ---------- ff2 + residual (uses w2f; prefetch next wqf) ----------
    {
      if (l == 0) {
        const bf16x8* wq1 = (const bf16x8*)(wbf + 28672 + 131072);
#pragma unroll
        for (int p = 0; p < 3; p++)
#pragma unroll
          for (int ks = 0; ks < 4; ks++)
            wqf[p * 4 + ks] = wq1[((p * 8 + w8) * 4 + ks) * 64 + lane];
      }
      f32x4 acc[4];
      f32x4 bias = *(const f32x4*)(f2b + l * 128 + 16 * w8 + 4 * g);
#pragma unroll
      for (int nt = 0; nt < 4; nt++) acc[nt] = bias;
#pragma unroll
      for (int ks = 0; ks < 8; ks++) {
        bf16x8 Bf[4];
#pragma unroll
        for (int nt = 0; nt < 4; nt++) {
          s16x4 lo = *(const s16x4*)&ubuf[FI(16 * nt + c, 32 * ks + 4 * g)];
          s16x4 hi = *(const s16x4*)&ubuf[FI(16 * nt + c, 32 * ks + 16 + 4 * g)];
          Bf[nt] = __builtin_shufflevector(lo, hi, 0, 1, 2, 3, 4, 5, 6, 7);
        }
#pragma unroll
        for (int nt = 0; nt < 4; nt++)
          acc[nt] = __builtin_amdgcn_mfma_f32_16x16x32_bf16(w2f[ks], Bf[nt], acc[nt], 0, 0, 0);
      }
#pragma unroll
      for (int nt = 0; nt < 4; nt++) {
        float* yp = &ylds[YI(16 * nt + c, 16 * w8 + 4 * g)];
        *(f32x4*)yp = *(const f32x4*)yp + acc[nt];
      }
    }
    __syncthreads();
    // ---------- LN2 ----------
    {
      const int t = 8 * w8 + (lane >> 3);
      const int s = lane & 7;
      f32x4 vv[4];
      float s1 = 0.f, s2 = 0.f;
#pragma unroll
      for (int k = 0; k < 4; k++) {
        vv[k] = *(const f32x4*)&ylds[YI(t, s * 16 + 4 * k)];
#pragma unroll
        for (int r = 0; r < 4; r++) { s1 += vv[k][r]; s2 = fmaf(vv[k][r], vv[k][r], s2); }
      }
      s1 += __shfl_xor(s1, 1, 64); s1 += __shfl_xor(s1, 2, 64); s1 += __shfl_xor(s1, 4, 64);
      s2 += __shfl_xor(s2, 1, 64); s2 += __shfl_xor(s2, 2, 64); s2 += __shfl_xor(s2, 4, 64);
      const float mean = s1 * 0.0078125f;
      const float var  = s2 * 0.0078125f - mean * mean;
      const float inv  = rsqrtf(var + EPSV);
#pragma unroll
      for (int k = 0; k < 4; k++) {
        f32x4 gg = *(const f32x4*)(l2g + l * 128 + s * 16 + 4 * k);
        f32x4 bb = *(const f32x4*)(l2b + l * 128 + s * 16 + 4 * k);
        f32x4 o;
#pragma unroll
        for (int r = 0; r < 4; r++) o[r] = (vv[k][r] - mean) * inv * gg[r] + bb[r];
        *(f32x4*)&ylds[YI(t, s * 16 + 4 * k)] = o;
      }
    }
    __syncthreads();
  }

  if (tid < 128) zbuf[b * 256 + tid] = ylds[YI(0, tid)];
  else if (tid < 256) zbuf[b * 256 + tid] = ylds[YI(flb, tid - 128)];
}

// ---------------- classifier head (live BN), 4-way ILP accumulators ----------------
__global__ __launch_bounds__(256) void head_kernel(
    const float* __restrict__ zbuf,
    const float* __restrict__ fc1w, const float* __restrict__ fc1b,
    const float* __restrict__ bn1g, const float* __restrict__ bn1b,
    const float* __restrict__ fc15w, const float* __restrict__ fc15b,
    const float* __restrict__ bn15g, const float* __restrict__ bn15b,
    const float* __restrict__ fc2w, const float* __restrict__ fc2b,
    const float* __restrict__ bn2g, const float* __restrict__ bn2b,
    const float* __restrict__ fcw, const float* __restrict__ fcb,
    float* __restrict__ out)
{
  __shared__ float zc[16 * 256];
  __shared__ float t1[16 * 128];
  __shared__ float t15[16 * 64];
  __shared__ float t2[16 * 32];
  const int tid = threadIdx.x;

  for (int idx = tid; idx < 16 * 256; idx += 256) zc[idx] = zbuf[idx];
  __syncthreads();

  for (int idx = tid; idx < 16 * 128; idx += 256) {
    const int b = idx >> 7, j = idx & 127;
    const float* zr = zc + b * 256;
    float a0 = 0.f, a1 = 0.f, a2 = 0.f, a3 = 0.f;
    for (int k = 0; k < 256; k += 4) {
      a0 = fmaf(zr[k],     fc1w[k * 128 + j],       a0);
      a1 = fmaf(zr[k + 1], fc1w[(k + 1) * 128 + j], a1);
      a2 = fmaf(zr[k + 2], fc1w[(k + 2) * 128 + j], a2);
      a3 = fmaf(zr[k + 3], fc1w[(k + 3) * 128 + j], a3);
    }
    t1[idx] = fc1b[j] + ((a0 + a1) + (a2 + a3));
  }
  __syncthreads();
  if (tid < 128) {
    const int j = tid;
    float s1 = 0.f, s2 = 0.f;
    for (int b = 0; b < 16; b++) { const float v = t1[b * 128 + j]; s1 += v; s2 = fmaf(v, v, s2); }
    const float m = s1 * (1.f / 16.f);
    const float var = s2 * (1.f / 16.f) - m * m;
    const float scl = bn1g[j] / sqrtf(var + EPSV);
    const float sh = bn1b[j] - m * scl;
    for (int b = 0; b < 16; b++) {
      const float v = t1[b * 128 + j] * scl + sh;
      t1[b * 128 + j] = (v > 0.f) ? v : 0.2f * v;
    }
  }
  __syncthreads();

  for (int idx = tid; idx < 16 * 64; idx += 256) {
    const int b = idx >> 6, j = idx & 63;
    const float* tr = t1 + b * 128;
    float a0 = 0.f, a1 = 0.f, a2 = 0.f, a3 = 0.f;
    for (int k = 0; k < 128; k += 4) {
      a0 = fmaf(tr[k],     fc15w[k * 64 + j],       a0);
      a1 = fmaf(tr[k + 1], fc15w[(k + 1) * 64 + j], a1);
      a2 = fmaf(tr[k + 2], fc15w[(k + 2) * 64 + j], a2);
      a3 = fmaf(tr[k + 3], fc15w[(k + 3) * 64 + j], a3);
    }
    t15[idx] = fc15b[j] + ((a0 + a1) + (a2 + a3));
  }
  __syncthreads();
  if (tid < 64) {
    const int j = tid;
    float s1 = 0.f, s2 = 0.f;
    for (int b = 0; b < 16; b++) { const float v = t15[b * 64 + j]; s1 += v; s2 = fmaf(v, v, s2); }
    const float m = s1 * (1.f / 16.f);
    const float var = s2 * (1.f / 16.f) - m * m;
    const float scl = bn15g[j] / sqrtf(var + EPSV);
    const float sh = bn15b[j] - m * scl;
    for (int b = 0; b < 16; b++) {
      const float v = t15[b * 64 + j] * scl + sh;
      t15[b * 64 + j] = (v > 0.f) ? v : 0.2f * v;
    }
  }
  __syncthreads();

  for (int idx = tid; idx < 16 * 32; idx += 256) {
    const int b = idx >> 5, j = idx & 31;
    const float* tr = t15 + b * 64;
    float a0 = 0.f, a1 = 0.f, a2 = 0.f, a3 = 0.f;
    for (int k = 0; k < 64; k += 4) {
      a0 = fmaf(tr[k],     fc2w[k * 32 + j],       a0);
      a1 = fmaf(tr[k + 1], fc2w[(k + 1) * 32 + j], a1);
      a2 = fmaf(tr[k + 2], fc2w[(k + 2) * 32 + j], a2);
      a3 = fmaf(tr[k + 3], fc2w[(k + 3) * 32 + j], a3);
    }
    t2[idx] = fc2b[j] + ((a0 + a1) + (a2 + a3));
  }
  __syncthreads();
  if (tid < 32) {
    const int j = tid;
    float s1 = 0.f, s2 = 0.f;
    for (int b = 0; b < 16; b++) { const float v = t2[b * 32 + j]; s1 += v; s2 = fmaf(v, v, s2); }
    const float m = s1 * (1.f / 16.f);
    const float var = s2 * (1.f / 16.f) - m * m;
    const float scl = bn2g[j] / sqrtf(var + EPSV);
    const float sh = bn2b[j] - m * scl;
    for (int b = 0; b < 16; b++) {
      const float v = t2[b * 32 + j] * scl + sh;
      t2[b * 32 + j] = (v > 0.f) ? v : 0.2f * v;
    }
  }
  __syncthreads();

  for (int idx = tid; idx < 16 * 27; idx += 256) {
    const int b = idx / 27, cc = idx % 27;
    float a = fcb[cc];
    for (int k = 0; k < 32; k++) a = fmaf(t2[b * 32 + k], fcw[k * 27 + cc], a);
    out[b * 27 + cc] = a;
  }
}

extern "C" void kernel_launch(void* const* d_in, const int* in_sizes, int n_in,
                              void* d_out, int out_size, void* d_ws, size_t ws_size,
                              hipStream_t stream)
{
  const float* x    = (const float*)d_in[0];
  const int*   fl   = (const int*)d_in[1];
  const float* ew1  = (const float*)d_in[2];  const float* eb1 = (const float*)d_in[3];
  const float* ew2  = (const float*)d_in[4];  const float* eb2 = (const float*)d_in[5];
  const float* ew3  = (const float*)d_in[6];  const float* eb3 = (const float*)d_in[7];
  const float* ctok = (const float*)d_in[8];  const float* cpos = (const float*)d_in[9];
  const float* in_w = (const float*)d_in[10]; const float* in_b = (const float*)d_in[11];
  const float* ow   = (const float*)d_in[12]; const float* ob   = (const float*)d_in[13];
  const float* l1g  = (const float*)d_in[14]; const float* l1b  = (const float*)d_in[15];
  const float* f1w  = (const float*)d_in[16]; const float* f1b  = (const float*)d_in[17];
  const float* f2w  = (const float*)d_in[18]; const float* f2b  = (const float*)d_in[19];
  const float* l2g  = (const float*)d_in[20]; const float* l2b  = (const float*)d_in[21];
  const float* fc1w = (const float*)d_in[22]; const float* fc1b = (const float*)d_in[23];
  const float* bn1g = (const float*)d_in[24]; const float* bn1b = (const float*)d_in[25];
  const float* fc15w= (const float*)d_in[26]; const float* fc15b= (const float*)d_in[27];
  const float* bn15g= (const float*)d_in[28]; const float* bn15b= (const float*)d_in[29];
  const float* fc2w = (const float*)d_in[30]; const float* fc2b = (const float*)d_in[31];
  const float* bn2g = (const float*)d_in[32]; const float* bn2b = (const float*)d_in[33];
  const float* fcw  = (const float*)d_in[34]; const float* fcb  = (const float*)d_in[35];
  float* out = (float*)d_out;

  char* w = (char*)d_ws;
  float* ymax = (float*)w;                                   // 491520 B
  float* zbuf = (float*)(w + 491520);                        // 16384 B
  unsigned short* wbf = (unsigned short*)(w + 507904);       // 568 frags * 1024 B = 581632 B

  prep_kernel<<<1136, 256, 0, stream>>>(ew1, eb1, ew2, ew3, in_w, ow, f1w, f2w, wbf);
  enc_kernel<<<960, 256, 0, stream>>>(x, eb2, eb3, wbf, ymax);
  xformer_kernel<<<16, 512, 0, stream>>>(ymax, fl, ctok, cpos, wbf, in_b, ob,
                                         l1g, l1b, f1b, f2b, l2g, l2b, zbuf);
  head_kernel<<<1, 256, 0, stream>>>(zbuf, fc1w, fc1b, bn1g, bn1b,
                                     fc15w, fc15b, bn15g, bn15b,
                                     fc2w, fc2b, bn2g, bn2b, fcw, fcb, out);
}

// Round 6
// 80.370 us; speedup vs baseline: 9.2064x; 1.3362x over previous
//
#include <hip/hip_runtime.h>
#include <math.h>

#define SS 61
#define EPSV 1e-5f

typedef __attribute__((ext_vector_type(8))) short bf16x8;
typedef __attribute__((ext_vector_type(4))) short s16x4;
typedef __attribute__((ext_vector_type(4))) float f32x4;

__device__ __forceinline__ short f2bf(float f){
  return __builtin_bit_cast(short, (__bf16)f);
}
__device__ __forceinline__ float bf2f(short s){
  unsigned u = ((unsigned)(unsigned short)s) << 16;
  return __builtin_bit_cast(float, u);
}
__device__ __forceinline__ bf16x8 pack8(f32x4 lo, f32x4 hi){
  bf16x8 r;
  r[0]=f2bf(lo[0]); r[1]=f2bf(lo[1]); r[2]=f2bf(lo[2]); r[3]=f2bf(lo[3]);
  r[4]=f2bf(hi[0]); r[5]=f2bf(hi[1]); r[6]=f2bf(hi[2]); r[7]=f2bf(hi[3]);
  return r;
}
__device__ __forceinline__ s16x4 pack4(f32x4 v){
  s16x4 r; r[0]=f2bf(v[0]); r[1]=f2bf(v[1]); r[2]=f2bf(v[2]); r[3]=f2bf(v[3]); return r;
}
// xformer swizzles (verified R3-R5)
#define YI(t,d) (((t)<<7) + ((d) ^ (((t)&7)<<2)))
#define OI(t,e) (((t)<<7) + ((e) ^ (((t)&7)<<2)))
#define FI(t,e) (((t)<<8) + ((e) ^ (((t)&7)<<2)))
#define VI(k,d) (((k)<<5) + ((d) ^ (((k)&7)<<2)))
// enc LDS (byte offsets, slot-ordered rows, XOR-swizzled 16B granules)
#define H1A(pt,idx) ((pt)*128 + (((idx)*2) ^ (((pt)&7)<<4)))
#define H2A(pt,idx) ((pt)*256 + (((idx)*2) ^ (((pt)&15)<<4)))

// ================= weight prep: fp32 -> bf16 fragment-linear =================
// frags: 0..3 A1hi, 4..7 A1lo, 8..23 A2, 24..55 A3,
//        56 + l*256: qkv 96 | ow 32 | f1 64 | f2 64,
//        568..631 fc1 hi | 632..695 fc1 lo | 696..711 fc15 hi | 712..727 fc15 lo
//        728..731 fc2 hi | 732..735 fc2 lo | 736..737 fcw hi | 738..739 fcw lo
__global__ __launch_bounds__(256) void prep_kernel(
    const float* __restrict__ ew1, const float* __restrict__ eb1,
    const float* __restrict__ ew2, const float* __restrict__ ew3,
    const float* __restrict__ in_w, const float* __restrict__ ow,
    const float* __restrict__ f1w, const float* __restrict__ f2w,
    const float* __restrict__ fc1w, const float* __restrict__ fc15w,
    const float* __restrict__ fc2w, const float* __restrict__ fcw,
    unsigned short* __restrict__ wbf)
{
  int s = blockIdx.x * 256 + threadIdx.x;   // 0..378879
  int i = s & 7, lane = (s >> 3) & 63, frag = s >> 9;
  int c = lane & 15, g = lane >> 4;
  int sig = 16 * (i >> 2) + 4 * g + (i & 3);
  unsigned short outv;
  if (frag < 8) {
    int mt = frag & 3;
    float base = (sig < 3) ? ew1[sig * 64 + 16 * mt + c]
               : (sig == 3 ? eb1[16 * mt + c] : 0.f);
    short hv = f2bf(base);
    if (frag < 4) outv = (unsigned short)hv;
    else { float rv = base - bf2f(hv); outv = (unsigned short)f2bf(rv); }
  } else if (frag < 24) {
    int f = frag - 8; int mt = f >> 1, ks = f & 1;
    outv = (unsigned short)f2bf(ew2[(32 * ks + sig) * 128 + 16 * mt + c]);
  } else if (frag < 56) {
    int f = frag - 24; int mt = f >> 2, ks = f & 3;
    outv = (unsigned short)f2bf(ew3[(32 * ks + sig) * 128 + 16 * mt + c]);
  } else if (frag < 568) {
    int f = frag - 56; int l = f >> 8; f &= 255;
    float v;
    if (f < 96) { int tq = f >> 2, ks = f & 3;
      v = in_w[(size_t)l * 49152 + (size_t)(16 * tq + c) * 128 + 32 * ks + sig]; }
    else if (f < 128) { int f3 = f - 96; int t = f3 >> 2, ks = f3 & 3;
      v = ow[(size_t)l * 16384 + (size_t)(16 * t + c) * 128 + 32 * ks + sig]; }
    else if (f < 192) { int f3 = f - 128; int t = f3 >> 2, ks = f3 & 3;
      v = f1w[(size_t)l * 32768 + (size_t)(16 * t + c) * 128 + 32 * ks + sig]; }
    else { int f3 = f - 192; int t = f3 >> 3, ks = f3 & 7;
      v = f2w[(size_t)l * 32768 + (size_t)(16 * t + c) * 256 + 32 * ks + sig]; }
    outv = (unsigned short)f2bf(v);
  } else {
    int f = frag - 568;   // 0..171, head weights hi/lo
    float v; int hl;
    if (f < 128) { hl = f >> 6; int f6 = f & 63; int mt = f6 >> 3, ks = f6 & 7;
      v = fc1w[(32 * ks + sig) * 128 + 16 * mt + c]; }
    else if (f < 160) { int f2_ = f - 128; hl = f2_ >> 4; int f4 = f2_ & 15; int mt = f4 >> 2, ks = f4 & 3;
      v = fc15w[(32 * ks + sig) * 64 + 16 * mt + c]; }
    else if (f < 168) { int f2_ = f - 160; hl = f2_ >> 2; int f4 = f2_ & 3; int mt = f4 >> 1, ks = f4 & 1;
      v = fc2w[(32 * ks + sig) * 32 + 16 * mt + c]; }
    else { int f2_ = f - 168; hl = f2_ >> 1; int mt = f2_ & 1; int m = 16 * mt + c;
      v = (m < 27) ? fcw[sig * 27 + m] : 0.f; }
    short hv = f2bf(v);
    outv = hl ? (unsigned short)f2bf(v - bf2f(hv)) : (unsigned short)hv;
  }
  wbf[s] = outv;
}

// ====== encoder: cooperative 4-wave block, 1 frame/block, 64 pts/iter ======
__global__ __launch_bounds__(256) void enc_kernel(
    const float* __restrict__ x,
    const float* __restrict__ eb2, const float* __restrict__ eb3,
    const unsigned short* __restrict__ wbf,
    float* __restrict__ ymax)
{
  __shared__ __align__(16) unsigned short h1p[64 * 64];
  __shared__ __align__(16) unsigned short h2p[64 * 128];
  __shared__ float pmerge[2][128];
  const int tid = threadIdx.x, lane = tid & 63, wv = tid >> 6;
  const int c = lane & 15, g = lane >> 4;
  const int mh = wv & 1, gh = wv >> 1;
  const int frame = blockIdx.x;
  const bf16x8* wf = (const bf16x8*)wbf;

  bf16x8 A1h[4], A1l[4];
#pragma unroll
  for (int mt = 0; mt < 4; mt++) { A1h[mt] = wf[mt * 64 + lane]; A1l[mt] = wf[(4 + mt) * 64 + lane]; }
  bf16x8 A2f[4][2];
#pragma unroll
  for (int j = 0; j < 4; j++)
#pragma unroll
    for (int ks = 0; ks < 2; ks++) A2f[j][ks] = wf[(8 + (4 * mh + j) * 2 + ks) * 64 + lane];
  bf16x8 A3f[4][4];
#pragma unroll
  for (int j = 0; j < 4; j++)
#pragma unroll
    for (int ks = 0; ks < 4; ks++) A3f[j][ks] = wf[(24 + (4 * mh + j) * 4 + ks) * 64 + lane];
  f32x4 b2v[4];
#pragma unroll
  for (int j = 0; j < 4; j++) b2v[j] = *(const f32x4*)(eb2 + 16 * (4 * mh + j) + 4 * g);

  f32x4 pool[4];
#pragma unroll
  for (int j = 0; j < 4; j++) pool[j] = {-1e30f, -1e30f, -1e30f, -1e30f};

  const float* xf = x + (size_t)frame * 1536;
  float nx0, nx1, nx2;
  { const float* xp = xf + (16 * wv + c) * 3; nx0 = xp[0]; nx1 = xp[1]; nx2 = xp[2]; }

  const int ptw = 16 * wv + c;

  for (int t = 0; t < 8; t++) {
    const float x0 = nx0, x1 = nx1, x2 = nx2;
    if (t < 7) {
      const float* xp = xf + ((t + 1) * 64 + 16 * wv + c) * 3;
      nx0 = xp[0]; nx1 = xp[1]; nx2 = xp[2];
    }
    bf16x8 bxh = {0,0,0,0,0,0,0,0}, bxl = {0,0,0,0,0,0,0,0};
    if (g == 0) {
      short h0 = f2bf(x0), h1_ = f2bf(x1), h2_ = f2bf(x2);
      bxh[0] = h0; bxh[1] = h1_; bxh[2] = h2_; bxh[3] = (short)0x3F80;
      bxl[0] = f2bf(x0 - bf2f(h0)); bxl[1] = f2bf(x1 - bf2f(h1_)); bxl[2] = f2bf(x2 - bf2f(h2_));
    }
#pragma unroll
    for (int mt = 0; mt < 4; mt++) {
      f32x4 a = {0.f, 0.f, 0.f, 0.f};
      a = __builtin_amdgcn_mfma_f32_16x16x32_bf16(A1h[mt], bxh, a, 0, 0, 0);
      a = __builtin_amdgcn_mfma_f32_16x16x32_bf16(A1h[mt], bxl, a, 0, 0, 0);
      a = __builtin_amdgcn_mfma_f32_16x16x32_bf16(A1l[mt], bxh, a, 0, 0, 0);
      f32x4 rl;
#pragma unroll
      for (int r = 0; r < 4; r++) rl[r] = fmaxf(a[r], 0.f);
      *(s16x4*)((char*)h1p + H1A(ptw, (mt >> 1) * 32 + g * 8 + (mt & 1) * 4)) = pack4(rl);
    }
    __syncthreads();
    bf16x8 B2[2][2];
#pragma unroll
    for (int gi = 0; gi < 2; gi++)
#pragma unroll
      for (int ks = 0; ks < 2; ks++) {
        const int pt = 16 * (2 * gh + gi) + c;
        B2[gi][ks] = *(const bf16x8*)((const char*)h1p + H1A(pt, ks * 32 + g * 8));
      }
#pragma unroll
    for (int j = 0; j < 4; j++)
#pragma unroll
      for (int gi = 0; gi < 2; gi++) {
        f32x4 a = b2v[j];
        a = __builtin_amdgcn_mfma_f32_16x16x32_bf16(A2f[j][0], B2[gi][0], a, 0, 0, 0);
        a = __builtin_amdgcn_mfma_f32_16x16x32_bf16(A2f[j][1], B2[gi][1], a, 0, 0, 0);
        f32x4 rl;
#pragma unroll
        for (int r = 0; r < 4; r++) rl[r] = fmaxf(a[r], 0.f);
        const int mt = 4 * mh + j;
        const int pt = 16 * (2 * gh + gi) + c;
        *(s16x4*)((char*)h2p + H2A(pt, (mt >> 1) * 32 + g * 8 + (mt & 1) * 4)) = pack4(rl);
      }
    __syncthreads();
    bf16x8 B3[2][4];
#pragma unroll
    for (int gi = 0; gi < 2; gi++)
#pragma unroll
      for (int ks = 0; ks < 4; ks++) {
        const int pt = 16 * (2 * gh + gi) + c;
        B3[gi][ks] = *(const bf16x8*)((const char*)h2p + H2A(pt, ks * 32 + g * 8));
      }
#pragma unroll
    for (int j = 0; j < 4; j++)
#pragma unroll
      for (int gi = 0; gi < 2; gi++) {
        f32x4 a = {0.f, 0.f, 0.f, 0.f};
        a = __builtin_amdgcn_mfma_f32_16x16x32_bf16(A3f[j][0], B3[gi][0], a, 0, 0, 0);
        a = __builtin_amdgcn_mfma_f32_16x16x32_bf16(A3f[j][1], B3[gi][1], a, 0, 0, 0);
        a = __builtin_amdgcn_mfma_f32_16x16x32_bf16(A3f[j][2], B3[gi][2], a, 0, 0, 0);
        a = __builtin_amdgcn_mfma_f32_16x16x32_bf16(A3f[j][3], B3[gi][3], a, 0, 0, 0);
#pragma unroll
        for (int r = 0; r < 4; r++) pool[j][r] = fmaxf(pool[j][r], a[r]);
      }
  }

#pragma unroll
  for (int j = 0; j < 4; j++)
#pragma unroll
    for (int r = 0; r < 4; r++) {
      float v = pool[j][r];
      v = fmaxf(v, __shfl_xor(v, 1, 64));
      v = fmaxf(v, __shfl_xor(v, 2, 64));
      v = fmaxf(v, __shfl_xor(v, 4, 64));
      v = fmaxf(v, __shfl_xor(v, 8, 64));
      pool[j][r] = v;
    }
  if (c == 0) {
#pragma unroll
    for (int j = 0; j < 4; j++)
      *(f32x4*)&pmerge[gh][64 * mh + 16 * j + 4 * g] = pool[j];
  }
  __syncthreads();
  if (tid < 128)
    ymax[(size_t)frame * 128 + tid] = fmaxf(pmerge[0][tid], pmerge[1][tid]) + eb3[tid];
}

// ====== fused transformer: 1 block/batch, 512 threads, in-phase W loads ======
__global__ __launch_bounds__(512, 1) void xformer_kernel(
    const float* __restrict__ ymax, const int* __restrict__ fl,
    const float* __restrict__ ctok, const float* __restrict__ cpos,
    const unsigned short* __restrict__ wbf,
    const float* __restrict__ in_b, const float* __restrict__ ob,
    const float* __restrict__ l1g, const float* __restrict__ l1b,
    const float* __restrict__ f1b, const float* __restrict__ f2b,
    const float* __restrict__ l2g, const float* __restrict__ l2b,
    float* __restrict__ zbuf)
{
  __shared__ __align__(16) float ylds[64 * 128];
  __shared__ __align__(16) unsigned short ubuf[64 * 256];
  __shared__ __align__(16) unsigned short kq4[2][8][4][64][4];
  const int b = blockIdx.x, tid = threadIdx.x;
  const int w8 = tid >> 6, lane = tid & 63, c = lane & 15, g = lane >> 4;
  const int h = w8 >> 1, sub = w8 & 1;
  const int flb = fl[b];
  const float scl = 0.17677669529663687f;

  for (int it = 0; it < 16; it++) {
    int idx = it * 512 + tid;
    int t = idx >> 7, d = idx & 127;
    float v;
    if (t == 0) v = ctok[d] + cpos[d];
    else if (t <= 60) {
      int f = t - 1;
      float ym = (f < flb) ? ymax[(size_t)(b * 60 + f) * 128 + d] : 0.f;
      float dv = __expf((float)(d & ~1) * (-0.07195578416f));
      float ang = (float)f * dv;
      v = ym + ((d & 1) ? __cosf(ang) : __sinf(ang));
    } else v = 0.f;
    ylds[YI(t, d)] = v;
  }
  __syncthreads();

  for (int l = 0; l < 2; l++) {
    const unsigned short* WL = wbf + 28672 + (size_t)l * 131072;
    const bf16x8* wq  = (const bf16x8*)WL;
    const bf16x8* wo  = (const bf16x8*)(WL + 49152);
    const bf16x8* w1p = (const bf16x8*)(WL + 65536);
    const bf16x8* w2p = (const bf16x8*)(WL + 98304);
    unsigned short* vb = ubuf + 8192 + h * 2048;

    // ---------- qkv ----------
    {
      bf16x8 yB[4][4];
#pragma unroll
      for (int nt = 0; nt < 4; nt++)
#pragma unroll
        for (int ks = 0; ks < 4; ks++) {
          f32x4 lo = *(const f32x4*)&ylds[YI(16 * nt + c, 32 * ks + 4 * g)];
          f32x4 hi = *(const f32x4*)&ylds[YI(16 * nt + c, 32 * ks + 16 + 4 * g)];
          yB[nt][ks] = pack8(lo, hi);
        }
#pragma unroll
      for (int p = 0; p < 3; p++) {
        const int tq = p * 8 + w8;
        bf16x8 Af[4];
#pragma unroll
        for (int ks = 0; ks < 4; ks++) Af[ks] = wq[(tq * 4 + ks) * 64 + lane];
        f32x4 bias = *(const f32x4*)(in_b + l * 384 + p * 128 + 16 * w8 + 4 * g);
        f32x4 acc[4];
#pragma unroll
        for (int nt = 0; nt < 4; nt++) acc[nt] = bias;
#pragma unroll
        for (int ks = 0; ks < 4; ks++)
#pragma unroll
          for (int nt = 0; nt < 4; nt++)
            acc[nt] = __builtin_amdgcn_mfma_f32_16x16x32_bf16(Af[ks], yB[nt][ks], acc[nt], 0, 0, 0);
        if (p == 2) {
#pragma unroll
          for (int nt = 0; nt < 4; nt++)
            *(s16x4*)&vb[VI(16 * nt + c, 16 * sub + 4 * g)] = pack4(acc[nt]);
        } else {
#pragma unroll
          for (int nt = 0; nt < 4; nt++) {
            f32x4 sv = acc[nt];
            if (p == 0) sv = sv * scl;
            *(s16x4*)&kq4[p][w8][nt][lane][0] = pack4(sv);
          }
        }
      }
    }
    __syncthreads();

    // ---------- attention ----------
    {
      bf16x8 Ak[4], Bq2[2];
#pragma unroll
      for (int kt = 0; kt < 4; kt++) {
        s16x4 lo = *(const s16x4*)&kq4[1][2 * h][kt][lane][0];
        s16x4 hi = *(const s16x4*)&kq4[1][2 * h + 1][kt][lane][0];
        Ak[kt] = __builtin_shufflevector(lo, hi, 0, 1, 2, 3, 4, 5, 6, 7);
      }
#pragma unroll
      for (int j = 0; j < 2; j++) {
        s16x4 lo = *(const s16x4*)&kq4[0][2 * h][2 * sub + j][lane][0];
        s16x4 hi = *(const s16x4*)&kq4[0][2 * h + 1][2 * sub + j][lane][0];
        Bq2[j] = __builtin_shufflevector(lo, hi, 0, 1, 2, 3, 4, 5, 6, 7);
      }
      f32x4 St[4][2];
#pragma unroll
      for (int kt = 0; kt < 4; kt++)
#pragma unroll
        for (int j = 0; j < 2; j++) {
          f32x4 z = {0.f, 0.f, 0.f, 0.f};
          St[kt][j] = __builtin_amdgcn_mfma_f32_16x16x32_bf16(Ak[kt], Bq2[j], z, 0, 0, 0);
        }
#pragma unroll
      for (int j = 0; j < 2; j++) {
        float m = -1e30f;
#pragma unroll
        for (int kt = 0; kt < 4; kt++)
#pragma unroll
          for (int r = 0; r < 4; r++) {
            const int kp = 16 * kt + 4 * g + r;
            float s = St[kt][j][r];
            s = (kp > flb) ? -1e30f : s;
            St[kt][j][r] = s;
            m = fmaxf(m, s);
          }
        m = fmaxf(m, __shfl_xor(m, 16, 64));
        m = fmaxf(m, __shfl_xor(m, 32, 64));
        float sum = 0.f;
#pragma unroll
        for (int kt = 0; kt < 4; kt++)
#pragma unroll
          for (int r = 0; r < 4; r++) {
            float p = __expf(St[kt][j][r] - m);
            St[kt][j][r] = p;
            sum += p;
          }
        sum += __shfl_xor(sum, 16, 64);
        sum += __shfl_xor(sum, 32, 64);
        const float inv = 1.f / sum;
#pragma unroll
        for (int kt = 0; kt < 4; kt++)
#pragma unroll
          for (int r = 0; r < 4; r++) St[kt][j][r] *= inv;
      }
      bf16x8 Bp[2][2];
#pragma unroll
      for (int j = 0; j < 2; j++)
#pragma unroll
        for (int ks = 0; ks < 2; ks++) {
          bf16x8 r;
#pragma unroll
          for (int i = 0; i < 8; i++) r[i] = f2bf(St[2 * ks + (i >> 2)][j][i & 3]);
          Bp[j][ks] = r;
        }
      bf16x8 Av[2][2];
#pragma unroll
      for (int dt = 0; dt < 2; dt++)
#pragma unroll
        for (int ks = 0; ks < 2; ks++) {
          bf16x8 r;
#pragma unroll
          for (int i = 0; i < 8; i++) {
            const int kp = 32 * ks + 16 * (i >> 2) + 4 * g + (i & 3);
            r[i] = (short)vb[VI(kp, 16 * dt + c)];
          }
          Av[dt][ks] = r;
        }
#pragma unroll
      for (int dt = 0; dt < 2; dt++)
#pragma unroll
        for (int j = 0; j < 2; j++) {
          f32x4 z = {0.f, 0.f, 0.f, 0.f};
          z = __builtin_amdgcn_mfma_f32_16x16x32_bf16(Av[dt][0], Bp[j][0], z, 0, 0, 0);
          z = __builtin_amdgcn_mfma_f32_16x16x32_bf16(Av[dt][1], Bp[j][1], z, 0, 0, 0);
          *(s16x4*)&ubuf[OI(16 * (2 * sub + j) + c, 32 * h + 16 * dt + 4 * g)] = pack4(z);
        }
    }
    __syncthreads();

    // ---------- proj + residual ----------
    {
      bf16x8 Bo[4][4];
#pragma unroll
      for (int nt = 0; nt < 4; nt++)
#pragma unroll
        for (int ks = 0; ks < 4; ks++) {
          s16x4 lo = *(const s16x4*)&ubuf[OI(16 * nt + c, 32 * ks + 4 * g)];
          s16x4 hi = *(const s16x4*)&ubuf[OI(16 * nt + c, 32 * ks + 16 + 4 * g)];
          Bo[nt][ks] = __builtin_shufflevector(lo, hi, 0, 1, 2, 3, 4, 5, 6, 7);
        }
      const int j0 = 16 * w8;
      bf16x8 Af[4];
#pragma unroll
      for (int ks = 0; ks < 4; ks++) Af[ks] = wo[(w8 * 4 + ks) * 64 + lane];
      f32x4 bias = *(const f32x4*)(ob + l * 128 + j0 + 4 * g);
      f32x4 acc[4];
#pragma unroll
      for (int nt = 0; nt < 4; nt++) acc[nt] = bias;
#pragma unroll
      for (int ks = 0; ks < 4; ks++)
#pragma unroll
        for (int nt = 0; nt < 4; nt++)
          acc[nt] = __builtin_amdgcn_mfma_f32_16x16x32_bf16(Af[ks], Bo[nt][ks], acc[nt], 0, 0, 0);
#pragma unroll
      for (int nt = 0; nt < 4; nt++) {
        float* yp = &ylds[YI(16 * nt + c, j0 + 4 * g)];
        *(f32x4*)yp = *(const f32x4*)yp + acc[nt];
      }
    }
    __syncthreads();
    // ---------- LN1 ----------
    {
      const int t = 8 * w8 + (lane >> 3);
      const int s = lane & 7;
      f32x4 vv[4];
      float s1 = 0.f, s2 = 0.f;
#pragma unroll
      for (int k = 0; k < 4; k++) {
        vv[k] = *(const f32x4*)&ylds[YI(t, s * 16 + 4 * k)];
#pragma unroll
        for (int r = 0; r < 4; r++) { s1 += vv[k][r]; s2 = fmaf(vv[k][r], vv[k][r], s2); }
      }
      s1 += __shfl_xor(s1, 1, 64); s1 += __shfl_xor(s1, 2, 64); s1 += __shfl_xor(s1, 4, 64);
      s2 += __shfl_xor(s2, 1, 64); s2 += __shfl_xor(s2, 2, 64); s2 += __shfl_xor(s2, 4, 64);
      const float mean = s1 * 0.0078125f;
      const float var  = s2 * 0.0078125f - mean * mean;
      const float inv  = rsqrtf(var + EPSV);
#pragma unroll
      for (int k = 0; k < 4; k++) {
        f32x4 gg = *(const f32x4*)(l1g + l * 128 + s * 16 + 4 * k);
        f32x4 bb = *(const f32x4*)(l1b + l * 128 + s * 16 + 4 * k);
        f32x4 o;
#pragma unroll
        for (int r = 0; r < 4; r++) o[r] = (vv[k][r] - mean) * inv * gg[r] + bb[r];
        *(f32x4*)&ylds[YI(t, s * 16 + 4 * k)] = o;
      }
    }
    __syncthreads();

    // ---------- ff1 (relu) ----------
    {
      bf16x8 yB[4][4];
#pragma unroll
      for (int nt = 0; nt < 4; nt++)
#pragma unroll
        for (int ks = 0; ks < 4; ks++) {
          f32x4 lo = *(const f32x4*)&ylds[YI(16 * nt + c, 32 * ks + 4 * g)];
          f32x4 hi = *(const f32x4*)&ylds[YI(16 * nt + c, 32 * ks + 16 + 4 * g)];
          yB[nt][ks] = pack8(lo, hi);
        }
#pragma unroll
      for (int half = 0; half < 2; half++) {
        const int t16 = 8 * half + w8;
        bf16x8 Af[4];
#pragma unroll
        for (int ks = 0; ks < 4; ks++) Af[ks] = w1p[(t16 * 4 + ks) * 64 + lane];
        f32x4 bias = *(const f32x4*)(f1b + l * 256 + 16 * t16 + 4 * g);
        f32x4 acc[4];
#pragma unroll
        for (int nt = 0; nt < 4; nt++) acc[nt] = bias;
#pragma unroll
        for (int ks = 0; ks < 4; ks++)
#pragma unroll
          for (int nt = 0; nt < 4; nt++)
            acc[nt] = __builtin_amdgcn_mfma_f32_16x16x32_bf16(Af[ks], yB[nt][ks], acc[nt], 0, 0, 0);
#pragma unroll
        for (int nt = 0; nt < 4; nt++) {
          f32x4 rl;
#pragma unroll
          for (int r = 0; r < 4; r++) rl[r] = fmaxf(acc[nt][r], 0.f);
          *(s16x4*)&ubuf[FI(16 * nt + c, 16 * t16 + 4 * g)] = pack4(rl);
        }
      }
    }
    __syncthreads();
    // ---------- ff2 + residual ----------
    {
      f32x4 acc[4];
      f32x4 bias = *(const f32x4*)(f2b + l * 128 + 16 * w8 + 4 * g);
#pragma unroll
      for (int nt = 0; nt < 4; nt++) acc[nt] = bias;
#pragma unroll
      for (int ks = 0; ks < 8; ks++) {
        bf16x8 Af = w2p[(w8 * 8 + ks) * 64 + lane];
        bf16x8 Bf[4];
#pragma unroll
        for (int nt = 0; nt < 4; nt++) {
          s16x4 lo = *(const s16x4*)&ubuf[FI(16 * nt + c, 32 * ks + 4 * g)];
          s16x4 hi = *(const s16x4*)&ubuf[FI(16 * nt + c, 32 * ks + 16 + 4 * g)];
          Bf[nt] = __builtin_shufflevector(lo, hi, 0, 1, 2, 3, 4, 5, 6, 7);
        }
#pragma unroll
        for (int nt = 0; nt < 4; nt++)
          acc[nt] = __builtin_amdgcn_mfma_f32_16x16x32_bf16(Af, Bf[nt], acc[nt], 0, 0, 0);
      }
#pragma unroll
      for (int nt = 0; nt < 4; nt++) {
        float* yp = &ylds[YI(16 * nt + c, 16 * w8 + 4 * g)];
        *(f32x4*)yp = *(const f32x4*)yp + acc[nt];
      }
    }
    __syncthreads();
    // ---------- LN2 ----------
    {
      const int t = 8 * w8 + (lane >> 3);
      const int s = lane & 7;
      f32x4 vv[4];
      float s1 = 0.f, s2 = 0.f;
#pragma unroll
      for (int k = 0; k < 4; k++) {
        vv[k] = *(const f32x4*)&ylds[YI(t, s * 16 + 4 * k)];
#pragma unroll
        for (int r = 0; r < 4; r++) { s1 += vv[k][r]; s2 = fmaf(vv[k][r], vv[k][r], s2); }
      }
      s1 += __shfl_xor(s1, 1, 64); s1 += __shfl_xor(s1, 2, 64); s1 += __shfl_xor(s1, 4, 64);
      s2 += __shfl_xor(s2, 1, 64); s2 += __shfl_xor(s2, 2, 64); s2 += __shfl_xor(s2, 4, 64);
      const float mean = s1 * 0.0078125f;
      const float var  = s2 * 0.0078125f - mean * mean;
      const float inv  = rsqrtf(var + EPSV);
#pragma unroll
      for (int k = 0; k < 4; k++) {
        f32x4 gg = *(const f32x4*)(l2g + l * 128 + s * 16 + 4 * k);
        f32x4 bb = *(const f32x4*)(l2b + l * 128 + s * 16 + 4 * k);
        f32x4 o;
#pragma unroll
        for (int r = 0; r < 4; r++) o[r] = (vv[k][r] - mean) * inv * gg[r] + bb[r];
        *(f32x4*)&ylds[YI(t, s * 16 + 4 * k)] = o;
      }
    }
    __syncthreads();
  }

  // classifier inputs, TRANSPOSED: zbuf[ch][b], ch 0..255
  if (tid < 256) {
    const int d = tid;
    float v = (d < 128) ? ylds[YI(0, d)] : ylds[YI(flb, d - 128)];
    zbuf[d * 16 + b] = v;
  }
}

// ====== head: MFMA hi/lo (≈fp32), transposed D[ch][batch], live BN over batch ======
__device__ __forceinline__ void buildB(const float* src, int ks, int g, int c,
                                       bf16x8& bh, bf16x8& bl){
#pragma unroll
  for (int i = 0; i < 8; i++) {
    int k = 32 * ks + 16 * (i >> 2) + 4 * g + (i & 3);
    float v = src[k * 16 + c];
    short hv = f2bf(v);
    bh[i] = hv; bl[i] = f2bf(v - bf2f(hv));
  }
}
__device__ __forceinline__ void bn_lrelu_store(f32x4 acc, int ch0, int c,
    const float* __restrict__ gg, const float* __restrict__ bb, float* dst){
#pragma unroll
  for (int r = 0; r < 4; r++) {
    float v = acc[r];
    float s1 = v, s2 = v * v;
    s1 += __shfl_xor(s1, 1, 64); s2 += __shfl_xor(s2, 1, 64);
    s1 += __shfl_xor(s1, 2, 64); s2 += __shfl_xor(s2, 2, 64);
    s1 += __shfl_xor(s1, 4, 64); s2 += __shfl_xor(s2, 4, 64);
    s1 += __shfl_xor(s1, 8, 64); s2 += __shfl_xor(s2, 8, 64);
    const float m = s1 * (1.f / 16.f);
    const float var = s2 * (1.f / 16.f) - m * m;
    const float scl = gg[ch0 + r] / sqrtf(var + EPSV);
    const float sh = bb[ch0 + r] - m * scl;
    float o = v * scl + sh;
    o = (o > 0.f) ? o : 0.2f * o;
    dst[(ch0 + r) * 16 + c] = o;
  }
}

__global__ __launch_bounds__(256, 1) void head_kernel(
    const float* __restrict__ zt, const unsigned short* __restrict__ wbf,
    const float* __restrict__ fc1b, const float* __restrict__ bn1g, const float* __restrict__ bn1b,
    const float* __restrict__ fc15b, const float* __restrict__ bn15g, const float* __restrict__ bn15b,
    const float* __restrict__ fc2b, const float* __restrict__ bn2g, const float* __restrict__ bn2b,
    const float* __restrict__ fcb, float* __restrict__ out)
{
  __shared__ float zs[256 * 16];
  __shared__ float t1s[128 * 16];
  __shared__ float t15s[64 * 16];
  __shared__ float t2s[32 * 16];
  const int tid = threadIdx.x, lane = tid & 63, wv = tid >> 6;
  const int c = lane & 15, g = lane >> 4;
  const bf16x8* wf = (const bf16x8*)wbf;

  for (int idx = tid; idx < 4096; idx += 256) zs[idx] = zt[idx];
  __syncthreads();

  // fc1: M=128 (wave -> mtiles 2wv,2wv+1), K=256
  {
    f32x4 acc[2];
#pragma unroll
    for (int j = 0; j < 2; j++) {
      const int ch0 = 16 * (2 * wv + j) + 4 * g;
      f32x4 a;
#pragma unroll
      for (int r = 0; r < 4; r++) a[r] = fc1b[ch0 + r];
      acc[j] = a;
    }
#pragma unroll
    for (int ks = 0; ks < 8; ks++) {
      bf16x8 bh, bl; buildB(zs, ks, g, c, bh, bl);
#pragma unroll
      for (int j = 0; j < 2; j++) {
        const int mt = 2 * wv + j;
        bf16x8 Ah = wf[(568 + mt * 8 + ks) * 64 + lane];
        bf16x8 Al = wf[(632 + mt * 8 + ks) * 64 + lane];
        acc[j] = __builtin_amdgcn_mfma_f32_16x16x32_bf16(Ah, bh, acc[j], 0, 0, 0);
        acc[j] = __builtin_amdgcn_mfma_f32_16x16x32_bf16(Ah, bl, acc[j], 0, 0, 0);
        acc[j] = __builtin_amdgcn_mfma_f32_16x16x32_bf16(Al, bh, acc[j], 0, 0, 0);
      }
    }
#pragma unroll
    for (int j = 0; j < 2; j++)
      bn_lrelu_store(acc[j], 16 * (2 * wv + j) + 4 * g, c, bn1g, bn1b, t1s);
  }
  __syncthreads();

  // fc15: M=64 (wave -> mtile wv), K=128
  {
    const int ch0 = 16 * wv + 4 * g;
    f32x4 a;
#pragma unroll
    for (int r = 0; r < 4; r++) a[r] = fc15b[ch0 + r];
#pragma unroll
    for (int ks = 0; ks < 4; ks++) {
      bf16x8 bh, bl; buildB(t1s, ks, g, c, bh, bl);
      bf16x8 Ah = wf[(696 + wv * 4 + ks) * 64 + lane];
      bf16x8 Al = wf[(712 + wv * 4 + ks) * 64 + lane];
      a = __builtin_amdgcn_mfma_f32_16x16x32_bf16(Ah, bh, a, 0, 0, 0);
      a = __builtin_amdgcn_mfma_f32_16x16x32_bf16(Ah, bl, a, 0, 0, 0);
      a = __builtin_amdgcn_mfma_f32_16x16x32_bf16(Al, bh, a, 0, 0, 0);
    }
    bn_lrelu_store(a, ch0, c, bn15g, bn15b, t15s);
  }
  __syncthreads();

  // fc2: M=32 (waves 0,1), K=64
  if (wv < 2) {
    const int ch0 = 16 * wv + 4 * g;
    f32x4 a;
#pragma unroll
    for (int r = 0; r < 4; r++) a[r] = fc2b[ch0 + r];
#pragma unroll
    for (int ks = 0; ks < 2; ks++) {
      bf16x8 bh, bl; buildB(t15s, ks, g, c, bh, bl);
      bf16x8 Ah = wf[(728 + wv * 2 + ks) * 64 + lane];
      bf16x8 Al = wf[(732 + wv * 2 + ks) * 64 + lane];
      a = __builtin_amdgcn_mfma_f32_16x16x32_bf16(Ah, bh, a, 0, 0, 0);
      a = __builtin_amdgcn_mfma_f32_16x16x32_bf16(Ah, bl, a, 0, 0, 0);
      a = __builtin_amdgcn_mfma_f32_16x16x32_bf16(Al, bh, a, 0, 0, 0);
    }
    bn_lrelu_store(a, ch0, c, bn2g, bn2b, t2s);
  }
  __syncthreads();

  // final fc: M=27 (waves 0,1), K=32, no BN
  if (wv < 2) {
    f32x4 a;
#pragma unroll
    for (int r = 0; r < 4; r++) {
      const int ch = 16 * wv + 4 * g + r;
      a[r] = (ch < 27) ? fcb[ch] : 0.f;
    }
    bf16x8 bh, bl; buildB(t2s, 0, g, c, bh, bl);
    bf16x8 Ah = wf[(736 + wv) * 64 + lane];
    bf16x8 Al = wf[(738 + wv) * 64 + lane];
    a = __builtin_amdgcn_mfma_f32_16x16x32_bf16(Ah, bh, a, 0, 0, 0);
    a = __builtin_amdgcn_mfma_f32_16x16x32_bf16(Ah, bl, a, 0, 0, 0);
    a = __builtin_amdgcn_mfma_f32_16x16x32_bf16(Al, bh, a, 0, 0, 0);
#pragma unroll
    for (int r = 0; r < 4; r++) {
      const int ch = 16 * wv + 4 * g + r;
      if (ch < 27) out[c * 27 + ch] = a[r];
    }
  }
}

extern "C" void kernel_launch(void* const* d_in, const int* in_sizes, int n_in,
                              void* d_out, int out_size, void* d_ws, size_t ws_size,
                              hipStream_t stream)
{
  const float* x    = (const float*)d_in[0];
  const int*   fl   = (const int*)d_in[1];
  const float* ew1  = (const float*)d_in[2];  const float* eb1 = (const float*)d_in[3];
  const float* ew2  = (const float*)d_in[4];  const float* eb2 = (const float*)d_in[5];
  const float* ew3  = (const float*)d_in[6];  const float* eb3 = (const float*)d_in[7];
  const float* ctok = (const float*)d_in[8];  const float* cpos = (const float*)d_in[9];
  const float* in_w = (const float*)d_in[10]; const float* in_b = (const float*)d_in[11];
  const float* ow   = (const float*)d_in[12]; const float* ob   = (const float*)d_in[13];
  const float* l1g  = (const float*)d_in[14]; const float* l1b  = (const float*)d_in[15];
  const float* f1w  = (const float*)d_in[16]; const float* f1b  = (const float*)d_in[17];
  const float* f2w  = (const float*)d_in[18]; const float* f2b  = (const float*)d_in[19];
  const float* l2g  = (const float*)d_in[20]; const float* l2b  = (const float*)d_in[21];
  const float* fc1w = (const float*)d_in[22]; const float* fc1b = (const float*)d_in[23];
  const float* bn1g = (const float*)d_in[24]; const float* bn1b = (const float*)d_in[25];
  const float* fc15w= (const float*)d_in[26]; const float* fc15b= (const float*)d_in[27];
  const float* bn15g= (const float*)d_in[28]; const float* bn15b= (const float*)d_in[29];
  const float* fc2w = (const float*)d_in[30]; const float* fc2b = (const float*)d_in[31];
  const float* bn2g = (const float*)d_in[32]; const float* bn2b = (const float*)d_in[33];
  const float* fcw  = (const float*)d_in[34]; const float* fcb  = (const float*)d_in[35];
  float* out = (float*)d_out;

  char* w = (char*)d_ws;
  float* ymax = (float*)w;                                   // 491520 B
  float* zbuf = (float*)(w + 491520);                        // 16384 B (transposed [ch][b])
  unsigned short* wbf = (unsigned short*)(w + 507904);       // 740 frags * 1024 B = 757760 B

  prep_kernel<<<1480, 256, 0, stream>>>(ew1, eb1, ew2, ew3, in_w, ow, f1w, f2w,
                                        fc1w, fc15w, fc2w, fcw, wbf);
  enc_kernel<<<960, 256, 0, stream>>>(x, eb2, eb3, wbf, ymax);
  xformer_kernel<<<16, 512, 0, stream>>>(ymax, fl, ctok, cpos, wbf, in_b, ob,
                                         l1g, l1b, f1b, f2b, l2g, l2b, zbuf);
  head_kernel<<<1, 256, 0, stream>>>(zbuf, wbf, fc1b, bn1g, bn1b,
                                     fc15b, bn15g, bn15b, fc2b, bn2g, bn2b, fcb, out);
}